// Round 7
// baseline (6279.755 us; speedup 1.0000x reference)
//
#include <hip/hip_runtime.h>
#include <hip/hip_cooperative_groups.h>
#include <hip/hip_bf16.h>

namespace cg = cooperative_groups;

#define NV    512           // N nodes
#define BN    1024          // B*N rows
#define NNB   30            // neighbors
#define DIM   64
#define HEADS 8
#define DH    128
#define INNER 1024          // HEADS*DH

// jax.nn.gelu default: approximate=True (tanh form)
__device__ __forceinline__ float gelu_t(float x){
    float x3 = x*x*x;
    return 0.5f*x*(1.0f + tanhf(0.7978845608028654f*(x + 0.044715f*x3)));
}
__device__ __forceinline__ unsigned short f2bf(float x){
    __hip_bfloat16 h = __float2bfloat16(x);           // RNE
    return __builtin_bit_cast(unsigned short, h);
}
__device__ __forceinline__ float bflo(unsigned u){ return __uint_as_float(u << 16); }
__device__ __forceinline__ float bfhi(unsigned u){ return __uint_as_float(u & 0xffff0000u); }

// =================================================================
// MEGA KERNEL — whole network in one cooperative launch.
// grid 1024 x 256. LDS 38,912 B (4 blocks/CU x 38.9K = 155.6K <= 160K).
// __launch_bounds__(256,4) => VGPR <= 128 => 16 waves/CU => co-resident.
// =================================================================
struct MP {
    const float *feats, *coors, *edges;
    const float *fe_w, *fe_b;
    const float *ln1_g, *ln1_b, *qkv_w, *out_w, *out_b;
    const float *ew1, *eb1, *ew2, *eb2, *cw1, *cb1, *cw2, *cb2;
    const float *c_scale, *c_comb;
    const float *ln2_g, *ln2_b, *fw1, *fb1, *fw2, *fb2;
    const float *cls_w, *cls_b;
    float *h; float *cA; float *cB; float *qf; unsigned short *kvh; int *idx;
    float *out;
};

struct ShmA { float At[64][68]; float Wt[64][64]; };                 // 33,792
struct ShmB { float qk[NNB][8]; float lg[NNB][8]; float t18[NNB][18];
              float t64[NNB][64]; float cwh[NNB][8]; float at[NNB][8];
              float ej[NNB]; float reln[NNB][3]; float wj[NNB]; int jid[NNB]; }; // 14,400
struct ShmC { float As[4][1024]; float Wc[64][64]; float hs[4][64];
              float ys[4][64]; float us[4][256]; };                  // 38,912

__global__ __launch_bounds__(256, 4) void k_mega(MP p){
    cg::grid_group grid = cg::this_grid();
    __shared__ __align__(16) unsigned char SM[sizeof(ShmC)];
    int bid = blockIdx.x, t = threadIdx.x;
    int wv = t >> 6, lane = t & 63;

    // ---------------- embed (block = row)
    {
        float* x = (float*)SM;
        int row = bid;
        if (t < 3){
            float f = p.feats[row*3+t];
            x[t]   = sinf(f);
            x[t+3] = cosf(f);
            p.cA[row*3+t] = p.coors[row*3+t];
        }
        __syncthreads();
        if (t < 64){
            float acc = p.fe_b[t];
            #pragma unroll
            for (int k = 0; k < 6; k++) acc += x[k]*p.fe_w[k*DIM+t];
            p.h[row*DIM+t] = fmaxf(acc, 0.0f);
        }
    }
    __threadfence();
    grid.sync();

    const float* cin = p.cA;
    float*       cot = p.cB;

    for (int l = 0; l < 8; l++){
        const float* ln1g = p.ln1_g + l*DIM;
        const float* ln1b = p.ln1_b + l*DIM;
        const float* qw   = p.qkv_w + (size_t)l*DIM*3*INNER;
        const float* ew1  = p.ew1 + l*9*18,  *eb1 = p.eb1 + l*18;
        const float* ew2  = p.ew2 + l*18*8,  *eb2 = p.eb2 + l*8;
        const float* cw1  = p.cw1 + l*8*64,  *cb1 = p.cb1 + l*64;
        const float* cw2  = p.cw2 + l*64*8,  *cb2 = p.cb2 + l*8;
        const float* csc  = p.c_scale + l,   *ccb = p.c_comb + l*8;
        const float* ow   = p.out_w + (size_t)l*INNER*DIM, *ob = p.out_b + l*DIM;
        const float* g2   = p.ln2_g + l*DIM, *b2 = p.ln2_b + l*DIM;
        const float* fw1  = p.fw1 + (size_t)l*DIM*256, *fb1 = p.fb1 + l*256;
        const float* fw2  = p.fw2 + (size_t)l*256*DIM, *fb2 = p.fb2 + l*64;

        // ======== phase A: qkv GEMM (bid<768: 16 row-tiles x 48 col-tiles of 64x64) | topk (bid>=768)
        if (bid < 768){
            ShmA& S = *reinterpret_cast<ShmA*>(SM);
            int rt = bid/48, ct = bid%48;
            int row0 = rt*64, col0 = ct*64;

            float gk = ln1g[lane], bk = ln1b[lane];
            #pragma unroll 4
            for (int rr = 0; rr < 16; rr++){
                int r = wv*16 + rr;
                float v = p.h[(row0+r)*DIM + lane];
                float s = v;
                #pragma unroll
                for (int m = 32; m >= 1; m >>= 1) s += __shfl_xor(s, m, 64);
                float mu = s*(1.0f/64.0f);
                float d = v - mu;
                float vv = d*d;
                #pragma unroll
                for (int m = 32; m >= 1; m >>= 1) vv += __shfl_xor(vv, m, 64);
                S.At[lane][r] = d / sqrtf(vv*(1.0f/64.0f) + 1e-5f) * gk + bk;
            }
            #pragma unroll
            for (int i = t*4; i < 64*64; i += 1024){
                int k = i >> 6, c = i & 63;
                *(float4*)&S.Wt[k][c] = *(const float4*)&qw[k*3072 + col0 + c];
            }
            __syncthreads();

            int ty = t >> 4, tx = t & 15;
            float acc[4][4];
            #pragma unroll
            for (int i = 0; i < 4; i++)
                #pragma unroll
                for (int j = 0; j < 4; j++) acc[i][j] = 0.0f;

            #pragma unroll 4
            for (int k = 0; k < 64; k++){
                float4 a  = *(const float4*)&S.At[k][ty*4];
                float4 w4 = *(const float4*)&S.Wt[k][tx*4];
                float av[4] = {a.x, a.y, a.z, a.w};
                float wj4[4] = {w4.x, w4.y, w4.z, w4.w};
                #pragma unroll
                for (int i = 0; i < 4; i++)
                    #pragma unroll
                    for (int j = 0; j < 4; j++) acc[i][j] += av[i]*wj4[j];
            }

            if (ct < 16){
                #pragma unroll
                for (int i = 0; i < 4; i++){
                    int r = row0 + ty*4 + i;
                    *(float4*)&p.qf[(size_t)r*INNER + col0 + tx*4] =
                        make_float4(acc[i][0], acc[i][1], acc[i][2], acc[i][3]);
                }
            } else {
                int kvcol0 = (ct-16)*64;
                #pragma unroll
                for (int i = 0; i < 4; i++){
                    int r = row0 + ty*4 + i;
                    ushort4 pk = { f2bf(acc[i][0]), f2bf(acc[i][1]), f2bf(acc[i][2]), f2bf(acc[i][3]) };
                    *(ushort4*)&p.kvh[(size_t)r*2048 + kvcol0 + tx*4] = pk;
                }
            }
        } else {
            // top-k 30, one wave per row
            int row = (bid - 768)*4 + wv;
            int b = row >> 9;
            const float* cbp = cin + (size_t)b*NV*3;
            float cx = cin[row*3+0], cy = cin[row*3+1], cz = cin[row*3+2];
            float d2[8];
            int jb = lane*8;
            #pragma unroll
            for (int u = 0; u < 8; u++){
                float dx = cx - cbp[(jb+u)*3+0];
                float dy = cy - cbp[(jb+u)*3+1];
                float dz = cz - cbp[(jb+u)*3+2];
                d2[u] = dx*dx + dy*dy + dz*dz;
            }
            for (int sel = 0; sel < NNB; sel++){
                float bv = d2[0]; int bu = 0;
                #pragma unroll
                for (int u = 1; u < 8; u++) if (d2[u] < bv){ bv = d2[u]; bu = u; }
                int bj = jb + bu;
                #pragma unroll
                for (int m = 32; m >= 1; m >>= 1){
                    float ov = __shfl_xor(bv, m, 64);
                    int   oj = __shfl_xor(bj, m, 64);
                    if (ov < bv || (ov == bv && oj < bj)){ bv = ov; bj = oj; }
                }
                if (lane == 0) p.idx[row*NNB + sel] = bj;
                #pragma unroll
                for (int u = 0; u < 8; u++) if (jb + u == bj) d2[u] = 1e30f;
            }
        }
        __threadfence();
        grid.sync();

        // ======== phase B: attention core (block = row)
        {
            ShmB& S = *reinterpret_cast<ShmB*>(SM);
            int row = bid;
            int b = row >> 9, i = row & (NV-1);

            if (t < NNB) S.jid[t] = p.idx[row*NNB + t];
            __syncthreads();

            float qreg[16];
            {
                const float4* qp = (const float4*)&p.qf[(size_t)row*INNER + lane*16];
                #pragma unroll
                for (int e = 0; e < 4; e++){
                    float4 v = qp[e];
                    qreg[e*4+0] = v.x; qreg[e*4+1] = v.y; qreg[e*4+2] = v.z; qreg[e*4+3] = v.w;
                }
            }

            if (t < NNB){
                int jj = S.jid[t];
                S.ej[t] = p.edges[(size_t)(b*NV+i)*NV + jj];
                float rx = cin[(b*NV+i)*3+0] - cin[(b*NV+jj)*3+0];
                float ry = cin[(b*NV+i)*3+1] - cin[(b*NV+jj)*3+1];
                float rz = cin[(b*NV+i)*3+2] - cin[(b*NV+jj)*3+2];
                float s = rx*rx + ry*ry + rz*rz;
                float den = fmaxf(sqrtf(s == 0.0f ? 1.0f : s), 1e-8f);
                float cs = csc[0];
                S.reln[t][0] = rx/den*cs;
                S.reln[t][1] = ry/den*cs;
                S.reln[t][2] = rz/den*cs;
            }

            // qk logits: wave-per-neighbor, q f32 regs x K bf16
            int part = lane & 7, hh = lane >> 3;
            #pragma unroll 2
            for (int j = wv; j < NNB; j += 4){
                int jj = S.jid[j];
                const uint4* kp = (const uint4*)&p.kvh[(size_t)(b*NV+jj)*2048 + lane*16];
                uint4 u0 = kp[0];
                uint4 u1 = kp[1];
                float acc = qreg[0]*bflo(u0.x) + qreg[1]*bfhi(u0.x)
                          + qreg[2]*bflo(u0.y) + qreg[3]*bfhi(u0.y)
                          + qreg[4]*bflo(u0.z) + qreg[5]*bfhi(u0.z)
                          + qreg[6]*bflo(u0.w) + qreg[7]*bfhi(u0.w);
                acc += qreg[8]*bflo(u1.x)  + qreg[9]*bfhi(u1.x)
                     + qreg[10]*bflo(u1.y) + qreg[11]*bfhi(u1.y)
                     + qreg[12]*bflo(u1.z) + qreg[13]*bfhi(u1.z)
                     + qreg[14]*bflo(u1.w) + qreg[15]*bfhi(u1.w);
                acc += __shfl_xor(acc, 1, 64);
                acc += __shfl_xor(acc, 2, 64);
                acc += __shfl_xor(acc, 4, 64);
                if (part == 0) S.qk[j][hh] = acc * 0.08838834764831845f;  // 1/sqrt(128)
            }
            __syncthreads();

            // edge MLP layer 1: (qk||e) (9) -> 18, gelu
            for (int id = t; id < NNB*18; id += 256){
                int j = id/18, u = id%18;
                float acc = eb1[u];
                #pragma unroll
                for (int k = 0; k < 8; k++) acc += S.qk[j][k]*ew1[k*18+u];
                acc += S.ej[j]*ew1[8*18+u];
                S.t18[j][u] = gelu_t(acc);
            }
            __syncthreads();
            // edge MLP layer 2: 18 -> 8
            if (t < NNB*HEADS){
                int j = t/HEADS, h2 = t%HEADS;
                float acc = eb2[h2];
                #pragma unroll
                for (int k = 0; k < 18; k++) acc += S.t18[j][k]*ew2[k*HEADS+h2];
                S.lg[j][h2] = acc;
            }
            __syncthreads();

            // coord MLP: gelu(lg) (8) -> 64 gelu -> 8
            for (int id = t; id < NNB*64; id += 256){
                int j = id/64, u = id%64;
                float acc = cb1[u];
                #pragma unroll
                for (int k = 0; k < 8; k++) acc += gelu_t(S.lg[j][k])*cw1[k*64+u];
                S.t64[j][u] = gelu_t(acc);
            }
            __syncthreads();
            if (t < NNB*HEADS){
                int j = t/HEADS, h2 = t%HEADS;
                float acc = cb2[h2];
                #pragma unroll 8
                for (int k = 0; k < 64; k++) acc += S.t64[j][k]*cw2[k*HEADS+h2];
                S.cwh[j][h2] = acc;
            }
            __syncthreads();

            if (t < NNB){
                float acc = 0.0f;
                #pragma unroll
                for (int h2 = 0; h2 < HEADS; h2++) acc += S.cwh[t][h2]*ccb[h2];
                S.wj[t] = acc;
            }
            if (t >= 64 && t < 64+HEADS){
                int h2 = t - 64;
                float m = -1e30f;
                for (int j = 0; j < NNB; j++) m = fmaxf(m, S.lg[j][h2]);
                float ll = 0.0f;
                for (int j = 0; j < NNB; j++){ float pr = expf(S.lg[j][h2]-m); S.at[j][h2] = pr; ll += pr; }
                float rl = 1.0f/ll;
                for (int j = 0; j < NNB; j++) S.at[j][h2] *= rl;
            }
            __syncthreads();

            // coordinate update
            if (t < 3){
                float acc = 0.0f;
                for (int j = 0; j < NNB; j++) acc += S.wj[j]*S.reln[j][t];
                cot[(b*NV+i)*3+t] = cin[(b*NV+i)*3+t] + acc;
            }

            // attn @ V (bf16): thread owns channels [t*4, t*4+4), head = t>>5
            int hv = t >> 5;
            float ax = 0.f, ay = 0.f, az = 0.f, aw = 0.f;
            for (int j = 0; j < NNB; j++){
                float a = S.at[j][hv];
                uint2 v = *(const uint2*)&p.kvh[(size_t)(b*NV+S.jid[j])*2048 + 1024 + t*4];
                ax += a*bflo(v.x); ay += a*bfhi(v.x); az += a*bflo(v.y); aw += a*bfhi(v.y);
            }
            *(float4*)&p.qf[(size_t)row*INNER + t*4] = make_float4(ax, ay, az, aw);
        }
        __threadfence();
        grid.sync();

        // ======== phase C: out-proj + residual + LN2 + FFN (bid < 256, 4 rows each)
        if (bid < 256){
            ShmC& S = *reinterpret_cast<ShmC*>(SM);
            int r0 = bid*4;

            #pragma unroll
            for (int i2 = 0; i2 < 4; i2++){
                int id = t*4 + i2*1024;
                int r = id >> 10, c = id & 1023;
                *(float4*)&S.As[r][c] = *(const float4*)&p.qf[(size_t)(r0+r)*INNER + c];
            }

            int r = t >> 6, c = t & 63;      // wave = row
            float acc = 0.0f;
            for (int ch = 0; ch < 16; ch++){
                __syncthreads();
                #pragma unroll
                for (int i2 = 0; i2 < 4; i2++){
                    int id = t*4 + i2*1024;
                    int k = id >> 6, cc = id & 63;
                    *(float4*)&S.Wc[k][cc] = *(const float4*)&ow[(size_t)(ch*64+k)*64 + cc];
                }
                __syncthreads();
                #pragma unroll 8
                for (int k = 0; k < 64; k++)
                    acc += S.As[r][ch*64+k]*S.Wc[k][c];
            }

            float v = p.h[(size_t)(r0+r)*DIM + c] + acc + ob[c];
            S.hs[r][c] = v;
            float s = v;
            #pragma unroll
            for (int m = 32; m >= 1; m >>= 1) s += __shfl_xor(s, m, 64);
            float mu = s*(1.0f/64.0f);
            float d = v - mu;
            float vv = d*d;
            #pragma unroll
            for (int m = 32; m >= 1; m >>= 1) vv += __shfl_xor(vv, m, 64);
            S.ys[r][c] = d / sqrtf(vv*(1.0f/64.0f) + 1e-5f) * g2[c] + b2[c];
            __syncthreads();

            float u0 = fb1[t], u1 = u0, u2 = u0, u3 = u0;
            #pragma unroll 8
            for (int k = 0; k < 64; k++){
                float w = fw1[k*256 + t];
                u0 += S.ys[0][k]*w; u1 += S.ys[1][k]*w; u2 += S.ys[2][k]*w; u3 += S.ys[3][k]*w;
            }
            S.us[0][t] = gelu_t(u0); S.us[1][t] = gelu_t(u1); S.us[2][t] = gelu_t(u2); S.us[3][t] = gelu_t(u3);
            __syncthreads();

            float f2 = fb2[c];
            #pragma unroll 8
            for (int k = 0; k < 256; k++) f2 += S.us[r][k]*fw2[k*DIM + c];
            p.h[(size_t)(r0+r)*DIM + c] = S.hs[r][c] + f2;
        }
        __threadfence();
        grid.sync();

        const float* tmp = cin; cin = cot; cot = (float*)tmp;
    }

    // ---------------- classifier + softmax (block = row)
    {
        float* lgs = (float*)SM;
        int row = bid;
        if (t < 20){
            float acc = p.cls_b[t];
            #pragma unroll 8
            for (int k = 0; k < 64; k++) acc += p.h[row*DIM+k]*p.cls_w[k*20+t];
            lgs[t] = acc;
        }
        __syncthreads();
        if (t < 20){
            float m = -1e30f;
            for (int c = 0; c < 20; c++) m = fmaxf(m, lgs[c]);
            float ll = 0.0f;
            for (int c = 0; c < 20; c++) ll += expf(lgs[c]-m);
            p.out[row*20+t] = expf(lgs[t]-m)/ll;
        }
    }
}

// =================================================================
// FALLBACK PATH (round-6 kernels) — used only if cooperative launch fails
// =================================================================
__global__ __launch_bounds__(64) void k_embed(const float* __restrict__ feats,
                                              const float* __restrict__ coors,
                                              const float* __restrict__ fe_w,
                                              const float* __restrict__ fe_b,
                                              float* __restrict__ h,
                                              float* __restrict__ coorsA){
    int row = blockIdx.x;
    int t = threadIdx.x;
    __shared__ float x[6];
    if (t < 3){
        float f = feats[row*3+t];
        x[t]   = sinf(f);
        x[t+3] = cosf(f);
        coorsA[row*3+t] = coors[row*3+t];
    }
    __syncthreads();
    float acc = fe_b[t];
    #pragma unroll
    for (int k = 0; k < 6; k++) acc += x[k]*fe_w[k*DIM+t];
    h[row*DIM+t] = fmaxf(acc, 0.0f);
}

__global__ __launch_bounds__(256) void k_head(const float* __restrict__ h,
                                              const float* __restrict__ g,
                                              const float* __restrict__ be,
                                              const float* __restrict__ w,
                                              float* __restrict__ qf,
                                              unsigned short* __restrict__ kvh,
                                              const float* __restrict__ coors,
                                              int* __restrict__ idx){
    __shared__ float At[64][68];
    __shared__ float Wt[64][132];
    int t = threadIdx.x;
    int wv = t >> 6, lane = t & 63;

    if (blockIdx.x < 384){
        int rt = blockIdx.x / 24, ct = blockIdx.x % 24;
        int row0 = rt*64, col0 = ct*128;

        float gk = g[lane], bk = be[lane];
        #pragma unroll 4
        for (int rr = 0; rr < 16; rr++){
            int r = wv*16 + rr;
            float v = h[(row0+r)*DIM + lane];
            float s = v;
            #pragma unroll
            for (int m = 32; m >= 1; m >>= 1) s += __shfl_xor(s, m, 64);
            float mu = s*(1.0f/64.0f);
            float d = v - mu;
            float vv = d*d;
            #pragma unroll
            for (int m = 32; m >= 1; m >>= 1) vv += __shfl_xor(vv, m, 64);
            At[lane][r] = d / sqrtf(vv*(1.0f/64.0f) + 1e-5f) * gk + bk;
        }
        const float* wg = w + col0;
        #pragma unroll
        for (int i = t*4; i < 64*128; i += 1024){
            int k = i >> 7, c = i & 127;
            *(float4*)&Wt[k][c] = *(const float4*)&wg[k*3072 + c];
        }
        __syncthreads();

        int ty = t >> 4, tx = t & 15;
        float acc[4][8];
        #pragma unroll
        for (int i = 0; i < 4; i++)
            #pragma unroll
            for (int j = 0; j < 8; j++) acc[i][j] = 0.0f;

        #pragma unroll 2
        for (int k = 0; k < 64; k++){
            float4 a  = *(const float4*)&At[k][ty*4];
            float4 w0 = *(const float4*)&Wt[k][tx*4];
            float4 w1 = *(const float4*)&Wt[k][64 + tx*4];
            float av[4]  = {a.x, a.y, a.z, a.w};
            float wv8[8] = {w0.x, w0.y, w0.z, w0.w, w1.x, w1.y, w1.z, w1.w};
            #pragma unroll
            for (int i = 0; i < 4; i++)
                #pragma unroll
                for (int j = 0; j < 8; j++) acc[i][j] += av[i]*wv8[j];
        }

        if (ct < 8){
            #pragma unroll
            for (int i = 0; i < 4; i++){
                int r = row0 + ty*4 + i;
                float* dst = &qf[(size_t)r*INNER + col0];
                *(float4*)&dst[tx*4]      = make_float4(acc[i][0], acc[i][1], acc[i][2], acc[i][3]);
                *(float4*)&dst[64 + tx*4] = make_float4(acc[i][4], acc[i][5], acc[i][6], acc[i][7]);
            }
        } else {
            int kvcol0 = col0 - 1024;
            #pragma unroll
            for (int i = 0; i < 4; i++){
                int r = row0 + ty*4 + i;
                unsigned short* dst = &kvh[(size_t)r*2048 + kvcol0];
                ushort4 p0 = { f2bf(acc[i][0]), f2bf(acc[i][1]), f2bf(acc[i][2]), f2bf(acc[i][3]) };
                ushort4 p1 = { f2bf(acc[i][4]), f2bf(acc[i][5]), f2bf(acc[i][6]), f2bf(acc[i][7]) };
                *(ushort4*)&dst[tx*4]      = p0;
                *(ushort4*)&dst[64 + tx*4] = p1;
            }
        }
    } else {
        int row = (blockIdx.x - 384)*4 + wv;
        int b = row >> 9;
        const float* cbp = coors + (size_t)b*NV*3;
        float cx = coors[row*3+0], cy = coors[row*3+1], cz = coors[row*3+2];
        float d2[8];
        int jb = lane*8;
        #pragma unroll
        for (int u = 0; u < 8; u++){
            float dx = cx - cbp[(jb+u)*3+0];
            float dy = cy - cbp[(jb+u)*3+1];
            float dz = cz - cbp[(jb+u)*3+2];
            d2[u] = dx*dx + dy*dy + dz*dz;
        }
        for (int sel = 0; sel < NNB; sel++){
            float bv = d2[0]; int bu = 0;
            #pragma unroll
            for (int u = 1; u < 8; u++) if (d2[u] < bv){ bv = d2[u]; bu = u; }
            int bj = jb + bu;
            #pragma unroll
            for (int m = 32; m >= 1; m >>= 1){
                float ov = __shfl_xor(bv, m, 64);
                int   oj = __shfl_xor(bj, m, 64);
                if (ov < bv || (ov == bv && oj < bj)){ bv = ov; bj = oj; }
            }
            if (lane == 0) idx[row*NNB + sel] = bj;
            #pragma unroll
            for (int u = 0; u < 8; u++) if (jb + u == bj) d2[u] = 1e30f;
        }
    }
}

__global__ __launch_bounds__(256) void k_attn(float* __restrict__ qf,
                                              const unsigned short* __restrict__ kvh,
                                              const int*   __restrict__ idx,
                                              const float* __restrict__ cin,
                                              float*       __restrict__ cout,
                                              const float* __restrict__ edges,
                                              const float* __restrict__ ew1, const float* __restrict__ eb1,
                                              const float* __restrict__ ew2, const float* __restrict__ eb2,
                                              const float* __restrict__ cw1, const float* __restrict__ cb1,
                                              const float* __restrict__ cw2, const float* __restrict__ cb2,
                                              const float* __restrict__ c_scale, const float* __restrict__ c_comb){
    int row = blockIdx.x;
    int b = row >> 9, i = row & (NV-1);
    int t = threadIdx.x;
    int wave = t >> 6, lane = t & 63;

    __shared__ float qk[NNB][HEADS];
    __shared__ float lg[NNB][HEADS];
    __shared__ float t18[NNB][18];
    __shared__ float t64s[NNB][64];
    __shared__ float cwh[NNB][HEADS];
    __shared__ float attn[NNB][HEADS];
    __shared__ float ej[NNB];
    __shared__ float reln[NNB][3];
    __shared__ float wj[NNB];
    __shared__ int   jid[NNB];

    if (t < NNB) jid[t] = idx[row*NNB + t];
    __syncthreads();

    float qreg[16];
    {
        const float4* qp = (const float4*)&qf[(size_t)row*INNER + lane*16];
        #pragma unroll
        for (int e = 0; e < 4; e++){
            float4 v = qp[e];
            qreg[e*4+0] = v.x; qreg[e*4+1] = v.y; qreg[e*4+2] = v.z; qreg[e*4+3] = v.w;
        }
    }

    if (t < NNB){
        int jj = jid[t];
        ej[t] = edges[(size_t)(b*NV+i)*NV + jj];
        float rx = cin[(b*NV+i)*3+0] - cin[(b*NV+jj)*3+0];
        float ry = cin[(b*NV+i)*3+1] - cin[(b*NV+jj)*3+1];
        float rz = cin[(b*NV+i)*3+2] - cin[(b*NV+jj)*3+2];
        float s = rx*rx + ry*ry + rz*rz;
        float den = fmaxf(sqrtf(s == 0.0f ? 1.0f : s), 1e-8f);
        float cs = c_scale[0];
        reln[t][0] = rx/den*cs;
        reln[t][1] = ry/den*cs;
        reln[t][2] = rz/den*cs;
    }

    int part = lane & 7, hh = lane >> 3;
    #pragma unroll 2
    for (int j = wave; j < NNB; j += 4){
        int jj = jid[j];
        const uint4* kp = (const uint4*)&kvh[(size_t)(b*NV+jj)*2048 + lane*16];
        uint4 u0 = kp[0];
        uint4 u1 = kp[1];
        float acc = qreg[0]*bflo(u0.x) + qreg[1]*bfhi(u0.x)
                  + qreg[2]*bflo(u0.y) + qreg[3]*bfhi(u0.y)
                  + qreg[4]*bflo(u0.z) + qreg[5]*bfhi(u0.z)
                  + qreg[6]*bflo(u0.w) + qreg[7]*bfhi(u0.w);
        acc += qreg[8]*bflo(u1.x)  + qreg[9]*bfhi(u1.x)
             + qreg[10]*bflo(u1.y) + qreg[11]*bfhi(u1.y)
             + qreg[12]*bflo(u1.z) + qreg[13]*bfhi(u1.z)
             + qreg[14]*bflo(u1.w) + qreg[15]*bfhi(u1.w);
        acc += __shfl_xor(acc, 1, 64);
        acc += __shfl_xor(acc, 2, 64);
        acc += __shfl_xor(acc, 4, 64);
        if (part == 0) qk[j][hh] = acc * 0.08838834764831845f;
    }
    __syncthreads();

    for (int id = t; id < NNB*18; id += 256){
        int j = id/18, u = id%18;
        float acc = eb1[u];
        #pragma unroll
        for (int k = 0; k < 8; k++) acc += qk[j][k]*ew1[k*18+u];
        acc += ej[j]*ew1[8*18+u];
        t18[j][u] = gelu_t(acc);
    }
    __syncthreads();
    if (t < NNB*HEADS){
        int j = t/HEADS, hh2 = t%HEADS;
        float acc = eb2[hh2];
        #pragma unroll
        for (int k = 0; k < 18; k++) acc += t18[j][k]*ew2[k*HEADS+hh2];
        lg[j][hh2] = acc;
    }
    __syncthreads();

    for (int id = t; id < NNB*64; id += 256){
        int j = id/64, u = id%64;
        float acc = cb1[u];
        #pragma unroll
        for (int k = 0; k < 8; k++) acc += gelu_t(lg[j][k])*cw1[k*64+u];
        t64s[j][u] = gelu_t(acc);
    }
    __syncthreads();
    if (t < NNB*HEADS){
        int j = t/HEADS, hh2 = t%HEADS;
        float acc = cb2[hh2];
        #pragma unroll 8
        for (int k = 0; k < 64; k++) acc += t64s[j][k]*cw2[k*HEADS+hh2];
        cwh[j][hh2] = acc;
    }
    __syncthreads();

    if (t < NNB){
        float acc = 0.0f;
        #pragma unroll
        for (int hh2 = 0; hh2 < HEADS; hh2++) acc += cwh[t][hh2]*c_comb[hh2];
        wj[t] = acc;
    }
    if (t >= 64 && t < 64+HEADS){
        int hh2 = t - 64;
        float m = -1e30f;
        for (int j = 0; j < NNB; j++) m = fmaxf(m, lg[j][hh2]);
        float l = 0.0f;
        for (int j = 0; j < NNB; j++){ float pr = expf(lg[j][hh2]-m); attn[j][hh2] = pr; l += pr; }
        float rl = 1.0f/l;
        for (int j = 0; j < NNB; j++) attn[j][hh2] *= rl;
    }
    __syncthreads();

    if (t < 3){
        float acc = 0.0f;
        for (int j = 0; j < NNB; j++) acc += wj[j]*reln[j][t];
        cout[(b*NV+i)*3+t] = cin[(b*NV+i)*3+t] + acc;
    }

    int hv = t >> 5;
    float ax = 0.f, ay = 0.f, az = 0.f, aw = 0.f;
    for (int j = 0; j < NNB; j++){
        float a = attn[j][hv];
        uint2 v = *(const uint2*)&kvh[(size_t)(b*NV+jid[j])*2048 + 1024 + t*4];
        ax += a*bflo(v.x); ay += a*bfhi(v.x); az += a*bflo(v.y); aw += a*bfhi(v.y);
    }
    *(float4*)&qf[(size_t)row*INNER + t*4] = make_float4(ax, ay, az, aw);
}

__global__ __launch_bounds__(256) void k_tail(const float* __restrict__ qf,
                                              float* __restrict__ h,
                                              const float* __restrict__ out_w, const float* __restrict__ out_b,
                                              const float* __restrict__ g2, const float* __restrict__ b2,
                                              const float* __restrict__ fw1, const float* __restrict__ fb1,
                                              const float* __restrict__ fw2, const float* __restrict__ fb2){
    __shared__ float As[4][1024];
    __shared__ float Wc[256][64];
    __shared__ float hs[4][64];
    __shared__ float ys[4][64];
    __shared__ float us[4][256];
    int t = threadIdx.x;
    int r0 = blockIdx.x*4;

    #pragma unroll
    for (int i2 = 0; i2 < 4; i2++){
        int id = t*4 + i2*1024;
        int r = id >> 10, c = id & 1023;
        *(float4*)&As[r][c] = *(const float4*)&qf[(size_t)(r0+r)*INNER + c];
    }

    int r = t >> 6, c = t & 63;
    float acc = 0.0f;
    for (int ch = 0; ch < 4; ch++){
        __syncthreads();
        #pragma unroll
        for (int i2 = 0; i2 < 16; i2++){
            int id = t*4 + i2*1024;
            int k = id >> 6, cc = id & 63;
            *(float4*)&Wc[k][cc] = *(const float4*)&out_w[(size_t)(ch*256+k)*64 + cc];
        }
        __syncthreads();
        #pragma unroll 8
        for (int k = 0; k < 256; k++)
            acc += As[r][ch*256+k]*Wc[k][c];
    }

    float v = h[(size_t)(r0+r)*DIM + c] + acc + out_b[c];
    hs[r][c] = v;
    float s = v;
    #pragma unroll
    for (int m = 32; m >= 1; m >>= 1) s += __shfl_xor(s, m, 64);
    float mu = s*(1.0f/64.0f);
    float d = v - mu;
    float vv = d*d;
    #pragma unroll
    for (int m = 32; m >= 1; m >>= 1) vv += __shfl_xor(vv, m, 64);
    ys[r][c] = d / sqrtf(vv*(1.0f/64.0f) + 1e-5f) * g2[c] + b2[c];
    __syncthreads();

    float u0 = fb1[t], u1 = u0, u2 = u0, u3 = u0;
    #pragma unroll 8
    for (int k = 0; k < 64; k++){
        float w = fw1[k*256 + t];
        u0 += ys[0][k]*w; u1 += ys[1][k]*w; u2 += ys[2][k]*w; u3 += ys[3][k]*w;
    }
    us[0][t] = gelu_t(u0); us[1][t] = gelu_t(u1); us[2][t] = gelu_t(u2); us[3][t] = gelu_t(u3);
    __syncthreads();

    float f2 = fb2[c];
    #pragma unroll 8
    for (int k = 0; k < 256; k++) f2 += us[r][k]*fw2[k*DIM + c];
    h[(size_t)(r0+r)*DIM + c] = hs[r][c] + f2;
}

__global__ __launch_bounds__(64) void k_cls(const float* __restrict__ h,
                                            const float* __restrict__ cls_w,
                                            const float* __restrict__ cls_b,
                                            float* __restrict__ out){
    int row = blockIdx.x;
    int t = threadIdx.x;
    __shared__ float lg[20];
    if (t < 20){
        float acc = cls_b[t];
        #pragma unroll 8
        for (int k = 0; k < 64; k++) acc += h[row*DIM+k]*cls_w[k*20+t];
        lg[t] = acc;
    }
    __syncthreads();
    if (t < 20){
        float m = -1e30f;
        for (int c = 0; c < 20; c++) m = fmaxf(m, lg[c]);
        float l = 0.0f;
        for (int c = 0; c < 20; c++) l += expf(lg[c]-m);
        out[row*20+t] = expf(lg[t]-m)/l;
    }
}

extern "C" void kernel_launch(void* const* d_in, const int* in_sizes, int n_in,
                              void* d_out, int out_size, void* d_ws, size_t ws_size,
                              hipStream_t stream) {
    const float* feats = (const float*)d_in[0];
    const float* coors = (const float*)d_in[1];
    const float* edges = (const float*)d_in[2];
    // d_in[3] = mask (all true) — unused
    const float* fe_w  = (const float*)d_in[4];
    const float* fe_b  = (const float*)d_in[5];
    const float* ln1_g = (const float*)d_in[6];
    const float* ln1_b = (const float*)d_in[7];
    const float* qkv_w = (const float*)d_in[8];
    const float* out_w = (const float*)d_in[9];
    const float* out_b = (const float*)d_in[10];
    const float* ew1   = (const float*)d_in[11];
    const float* eb1   = (const float*)d_in[12];
    const float* ew2   = (const float*)d_in[13];
    const float* eb2   = (const float*)d_in[14];
    const float* cw1   = (const float*)d_in[15];
    const float* cb1   = (const float*)d_in[16];
    const float* cw2   = (const float*)d_in[17];
    const float* cb2   = (const float*)d_in[18];
    const float* c_scale = (const float*)d_in[19];
    const float* c_comb  = (const float*)d_in[20];
    const float* ln2_g = (const float*)d_in[21];
    const float* ln2_b = (const float*)d_in[22];
    const float* fw1   = (const float*)d_in[23];
    const float* fb1   = (const float*)d_in[24];
    const float* fw2   = (const float*)d_in[25];
    const float* fb2   = (const float*)d_in[26];
    const float* cls_w = (const float*)d_in[27];
    const float* cls_b = (const float*)d_in[28];

    float* ws   = (float*)d_ws;
    float* h    = ws;                                  // 1024*64
    float* cA   = h + BN*DIM;                          // 1024*3
    float* cB   = cA + BN*3;                           // 1024*3
    float* qf   = cB + BN*3;                           // 1024*1024 f32: Q, then aout
    unsigned short* kvh = (unsigned short*)(qf + (size_t)BN*INNER); // 1024*2048 bf16: K|V
    int*   idx  = (int*)(kvh + (size_t)BN*2048);       // 1024*30

    MP P;
    P.feats = feats; P.coors = coors; P.edges = edges;
    P.fe_w = fe_w; P.fe_b = fe_b;
    P.ln1_g = ln1_g; P.ln1_b = ln1_b; P.qkv_w = qkv_w; P.out_w = out_w; P.out_b = out_b;
    P.ew1 = ew1; P.eb1 = eb1; P.ew2 = ew2; P.eb2 = eb2;
    P.cw1 = cw1; P.cb1 = cb1; P.cw2 = cw2; P.cb2 = cb2;
    P.c_scale = c_scale; P.c_comb = c_comb;
    P.ln2_g = ln2_g; P.ln2_b = ln2_b; P.fw1 = fw1; P.fb1 = fb1; P.fw2 = fw2; P.fb2 = fb2;
    P.cls_w = cls_w; P.cls_b = cls_b;
    P.h = h; P.cA = cA; P.cB = cB; P.qf = qf; P.kvh = kvh; P.idx = idx;
    P.out = (float*)d_out;

    void* args[] = { (void*)&P };
    hipError_t ce = hipLaunchCooperativeKernel((const void*)k_mega, dim3(1024), dim3(256),
                                               args, 0, stream);
    if (ce != hipSuccess){
        (void)hipGetLastError();   // clear, take the multi-launch fallback
        k_embed<<<BN, 64, 0, stream>>>(feats, coors, fe_w, fe_b, h, cA);
        float* cin = cA; float* cout = cB;
        for (int l = 0; l < 8; l++){
            k_head<<<640, 256, 0, stream>>>(h, ln1_g + l*DIM, ln1_b + l*DIM,
                                            qkv_w + (size_t)l*DIM*3*INNER,
                                            qf, kvh, cin, idx);
            k_attn<<<BN, 256, 0, stream>>>(qf, kvh, idx, cin, cout, edges,
                                           ew1 + l*9*18,  eb1 + l*18,
                                           ew2 + l*18*8,  eb2 + l*8,
                                           cw1 + l*8*64,  cb1 + l*64,
                                           cw2 + l*64*8,  cb2 + l*8,
                                           c_scale + l,   c_comb + l*8);
            k_tail<<<BN/4, 256, 0, stream>>>(qf, h,
                                             out_w + (size_t)l*INNER*DIM, out_b + l*DIM,
                                             ln2_g + l*DIM, ln2_b + l*DIM,
                                             fw1 + (size_t)l*DIM*256, fb1 + l*256,
                                             fw2 + (size_t)l*256*DIM, fb2 + l*64);
            float* tmp = cin; cin = cout; cout = tmp;
        }
        k_cls<<<BN, 64, 0, stream>>>(h, cls_w, cls_b, (float*)d_out);
    }
}

// Round 8
// 963.644 us; speedup vs baseline: 6.5167x; 6.5167x over previous
//
#include <hip/hip_runtime.h>
#include <hip/hip_bf16.h>

#define NV    512           // N nodes
#define BN    1024          // B*N rows
#define NNB   30            // neighbors
#define DIM   64
#define HEADS 8
#define DH    128
#define INNER 1024          // HEADS*DH

// jax.nn.gelu default: approximate=True (tanh form)
__device__ __forceinline__ float gelu_t(float x){
    float x3 = x*x*x;
    return 0.5f*x*(1.0f + tanhf(0.7978845608028654f*(x + 0.044715f*x3)));
}
__device__ __forceinline__ unsigned short f2bf(float x){
    __hip_bfloat16 h = __float2bfloat16(x);           // RNE
    return __builtin_bit_cast(unsigned short, h);
}
__device__ __forceinline__ float bflo(unsigned u){ return __uint_as_float(u << 16); }
__device__ __forceinline__ float bfhi(unsigned u){ return __uint_as_float(u & 0xffff0000u); }

// ---------------------------------------------------------------- embed
__global__ __launch_bounds__(64) void k_embed(const float* __restrict__ feats,
                                              const float* __restrict__ coors,
                                              const float* __restrict__ fe_w,
                                              const float* __restrict__ fe_b,
                                              float* __restrict__ h,
                                              float* __restrict__ coorsA){
    int row = blockIdx.x;
    int t = threadIdx.x;
    __shared__ float x[6];
    if (t < 3){
        float f = feats[row*3+t];
        x[t]   = sinf(f);
        x[t+3] = cosf(f);
        coorsA[row*3+t] = coors[row*3+t];
    }
    __syncthreads();
    float acc = fe_b[t];
    #pragma unroll
    for (int k = 0; k < 6; k++) acc += x[k]*fe_w[k*DIM+t];
    h[row*DIM+t] = fmaxf(acc, 0.0f);
}

// ---------------------------------------------------------------- fused head: LN1+qkv GEMM (blocks 0..383) | topk (blocks 384..639)
__global__ __launch_bounds__(256) void k_head(const float* __restrict__ h,
                                              const float* __restrict__ g,
                                              const float* __restrict__ be,
                                              const float* __restrict__ w,     // (64,3072)
                                              float* __restrict__ qf,
                                              unsigned short* __restrict__ kvh,
                                              const float* __restrict__ coors,
                                              int* __restrict__ idx){
    __shared__ float At[64][68];
    __shared__ float Wt[64][132];
    int t = threadIdx.x;
    int wv = t >> 6, lane = t & 63;

    if (blockIdx.x < 384){
        int rt = blockIdx.x / 24, ct = blockIdx.x % 24;
        int row0 = rt*64, col0 = ct*128;

        float gk = g[lane], bk = be[lane];
        #pragma unroll 4
        for (int rr = 0; rr < 16; rr++){
            int r = wv*16 + rr;
            float v = h[(row0+r)*DIM + lane];
            float s = v;
            #pragma unroll
            for (int m = 32; m >= 1; m >>= 1) s += __shfl_xor(s, m, 64);
            float mu = s*(1.0f/64.0f);
            float d = v - mu;
            float vv = d*d;
            #pragma unroll
            for (int m = 32; m >= 1; m >>= 1) vv += __shfl_xor(vv, m, 64);
            At[lane][r] = d / sqrtf(vv*(1.0f/64.0f) + 1e-5f) * gk + bk;
        }
        const float* wg = w + col0;
        #pragma unroll
        for (int i = t*4; i < 64*128; i += 1024){
            int k = i >> 7, c = i & 127;
            *(float4*)&Wt[k][c] = *(const float4*)&wg[k*3072 + c];
        }
        __syncthreads();

        int ty = t >> 4, tx = t & 15;
        float acc[4][8];
        #pragma unroll
        for (int i = 0; i < 4; i++)
            #pragma unroll
            for (int j = 0; j < 8; j++) acc[i][j] = 0.0f;

        #pragma unroll 2
        for (int k = 0; k < 64; k++){
            float4 a  = *(const float4*)&At[k][ty*4];
            float4 w0 = *(const float4*)&Wt[k][tx*4];
            float4 w1 = *(const float4*)&Wt[k][64 + tx*4];
            float av[4]  = {a.x, a.y, a.z, a.w};
            float wv8[8] = {w0.x, w0.y, w0.z, w0.w, w1.x, w1.y, w1.z, w1.w};
            #pragma unroll
            for (int i = 0; i < 4; i++)
                #pragma unroll
                for (int j = 0; j < 8; j++) acc[i][j] += av[i]*wv8[j];
        }

        if (ct < 8){
            #pragma unroll
            for (int i = 0; i < 4; i++){
                int r = row0 + ty*4 + i;
                float* dst = &qf[(size_t)r*INNER + col0];
                *(float4*)&dst[tx*4]      = make_float4(acc[i][0], acc[i][1], acc[i][2], acc[i][3]);
                *(float4*)&dst[64 + tx*4] = make_float4(acc[i][4], acc[i][5], acc[i][6], acc[i][7]);
            }
        } else {
            int kvcol0 = col0 - 1024;
            #pragma unroll
            for (int i = 0; i < 4; i++){
                int r = row0 + ty*4 + i;
                unsigned short* dst = &kvh[(size_t)r*2048 + kvcol0];
                ushort4 p0 = { f2bf(acc[i][0]), f2bf(acc[i][1]), f2bf(acc[i][2]), f2bf(acc[i][3]) };
                ushort4 p1 = { f2bf(acc[i][4]), f2bf(acc[i][5]), f2bf(acc[i][6]), f2bf(acc[i][7]) };
                *(ushort4*)&dst[tx*4]      = p0;
                *(ushort4*)&dst[64 + tx*4] = p1;
            }
        }
    } else {
        int row = (blockIdx.x - 384)*4 + wv;
        int b = row >> 9;
        const float* cbp = coors + (size_t)b*NV*3;
        float cx = coors[row*3+0], cy = coors[row*3+1], cz = coors[row*3+2];
        float d2[8];
        int jb = lane*8;
        #pragma unroll
        for (int u = 0; u < 8; u++){
            float dx = cx - cbp[(jb+u)*3+0];
            float dy = cy - cbp[(jb+u)*3+1];
            float dz = cz - cbp[(jb+u)*3+2];
            d2[u] = dx*dx + dy*dy + dz*dz;
        }
        for (int sel = 0; sel < NNB; sel++){
            float bv = d2[0]; int bu = 0;
            #pragma unroll
            for (int u = 1; u < 8; u++) if (d2[u] < bv){ bv = d2[u]; bu = u; }
            int bj = jb + bu;
            #pragma unroll
            for (int m = 32; m >= 1; m >>= 1){
                float ov = __shfl_xor(bv, m, 64);
                int   oj = __shfl_xor(bj, m, 64);
                if (ov < bv || (ov == bv && oj < bj)){ bv = ov; bj = oj; }
            }
            if (lane == 0) idx[row*NNB + sel] = bj;
            #pragma unroll
            for (int u = 0; u < 8; u++) if (jb + u == bj) d2[u] = 1e30f;
        }
    }
}

// ---------------------------------------------------------------- merged attention + tail
// 4 rows per block, 512 threads. Attention in 2 passes x 2 rows (half-block each),
// aout -> LDS As[4][1024]; then out-proj + residual + LN2 + FFN on t<256.
struct ShmB {
    float qk[NNB][HEADS];
    float lg[NNB][HEADS];
    float t18[NNB][18];
    float t64[NNB][64];
    float cwh[NNB][HEADS];
    float at[NNB][HEADS];
    float ej[NNB];
    float reln[NNB][3];
    float wj[NNB];
    int   jid[NNB];
};

__global__ __launch_bounds__(512) void k_attn4(const float* __restrict__ qf,
                                               const unsigned short* __restrict__ kvh,
                                               const int*   __restrict__ idx,
                                               const float* __restrict__ cin,
                                               float*       __restrict__ cout,
                                               const float* __restrict__ edges,
                                               float*       __restrict__ h,
                                               const float* __restrict__ ew1, const float* __restrict__ eb1,
                                               const float* __restrict__ ew2, const float* __restrict__ eb2,
                                               const float* __restrict__ cw1, const float* __restrict__ cb1,
                                               const float* __restrict__ cw2, const float* __restrict__ cb2,
                                               const float* __restrict__ c_scale, const float* __restrict__ c_comb,
                                               const float* __restrict__ out_w,  const float* __restrict__ out_b,
                                               const float* __restrict__ g2, const float* __restrict__ b2,
                                               const float* __restrict__ fw1, const float* __restrict__ fb1,
                                               const float* __restrict__ fw2, const float* __restrict__ fb2){
    __shared__ ShmB sb[2];
    __shared__ float As[4][1024];
    __shared__ float hs[4][64];
    __shared__ float ys[4][64];
    __shared__ float us[4][256];

    int t = threadIdx.x;
    int half = t >> 8, tt = t & 255;
    int lane = tt & 63, wv = tt >> 6;
    int r0 = blockIdx.x*4;

    // ================= attention: 2 passes x 2 rows =================
    for (int p = 0; p < 2; p++){
        ShmB& S = sb[half];
        int row = r0 + p*2 + half;
        int b = row >> 9, i = row & (NV-1);

        if (tt < NNB) S.jid[tt] = idx[row*NNB + tt];
        __syncthreads();

        // q in registers: lane owns dims [lane*16, lane*16+16)
        float qreg[16];
        {
            const float4* qp = (const float4*)&qf[(size_t)row*INNER + lane*16];
            #pragma unroll
            for (int e = 0; e < 4; e++){
                float4 v = qp[e];
                qreg[e*4+0] = v.x; qreg[e*4+1] = v.y; qreg[e*4+2] = v.z; qreg[e*4+3] = v.w;
            }
        }

        if (tt < NNB){
            int jj = S.jid[tt];
            S.ej[tt] = edges[(size_t)(b*NV+i)*NV + jj];
            float rx = cin[(b*NV+i)*3+0] - cin[(b*NV+jj)*3+0];
            float ry = cin[(b*NV+i)*3+1] - cin[(b*NV+jj)*3+1];
            float rz = cin[(b*NV+i)*3+2] - cin[(b*NV+jj)*3+2];
            float s = rx*rx + ry*ry + rz*rz;
            float den = fmaxf(sqrtf(s == 0.0f ? 1.0f : s), 1e-8f);
            float cs = c_scale[0];
            S.reln[tt][0] = rx/den*cs;
            S.reln[tt][1] = ry/den*cs;
            S.reln[tt][2] = rz/den*cs;
        }

        // qk logits: wave-per-neighbor (4 waves per half)
        int part = lane & 7, hh = lane >> 3;
        #pragma unroll 2
        for (int j = wv; j < NNB; j += 4){
            int jj = S.jid[j];
            const uint4* kp = (const uint4*)&kvh[(size_t)(b*NV+jj)*2048 + lane*16];
            uint4 u0 = kp[0];
            uint4 u1 = kp[1];
            float acc = qreg[0]*bflo(u0.x) + qreg[1]*bfhi(u0.x)
                      + qreg[2]*bflo(u0.y) + qreg[3]*bfhi(u0.y)
                      + qreg[4]*bflo(u0.z) + qreg[5]*bfhi(u0.z)
                      + qreg[6]*bflo(u0.w) + qreg[7]*bfhi(u0.w);
            acc += qreg[8]*bflo(u1.x)  + qreg[9]*bfhi(u1.x)
                 + qreg[10]*bflo(u1.y) + qreg[11]*bfhi(u1.y)
                 + qreg[12]*bflo(u1.z) + qreg[13]*bfhi(u1.z)
                 + qreg[14]*bflo(u1.w) + qreg[15]*bfhi(u1.w);
            acc += __shfl_xor(acc, 1, 64);
            acc += __shfl_xor(acc, 2, 64);
            acc += __shfl_xor(acc, 4, 64);
            if (part == 0) S.qk[j][hh] = acc * 0.08838834764831845f;  // 1/sqrt(128)
        }
        __syncthreads();

        // edge MLP layer 1: (qk||e) (9) -> 18, gelu
        for (int id = tt; id < NNB*18; id += 256){
            int j = id/18, u = id%18;
            float acc = eb1[u];
            #pragma unroll
            for (int k = 0; k < 8; k++) acc += S.qk[j][k]*ew1[k*18+u];
            acc += S.ej[j]*ew1[8*18+u];
            S.t18[j][u] = gelu_t(acc);
        }
        __syncthreads();
        // edge MLP layer 2: 18 -> 8
        if (tt < NNB*HEADS){
            int j = tt/HEADS, h2 = tt%HEADS;
            float acc = eb2[h2];
            #pragma unroll
            for (int k = 0; k < 18; k++) acc += S.t18[j][k]*ew2[k*HEADS+h2];
            S.lg[j][h2] = acc;
        }
        __syncthreads();

        // coord MLP: gelu(lg) (8) -> 64 gelu -> 8
        for (int id = tt; id < NNB*64; id += 256){
            int j = id/64, u = id%64;
            float acc = cb1[u];
            #pragma unroll
            for (int k = 0; k < 8; k++) acc += gelu_t(S.lg[j][k])*cw1[k*64+u];
            S.t64[j][u] = gelu_t(acc);
        }
        __syncthreads();
        if (tt < NNB*HEADS){
            int j = tt/HEADS, h2 = tt%HEADS;
            float acc = cb2[h2];
            #pragma unroll 8
            for (int k = 0; k < 64; k++) acc += S.t64[j][k]*cw2[k*HEADS+h2];
            S.cwh[j][h2] = acc;
        }
        __syncthreads();

        // per-neighbor coord weight, per-head softmax
        if (tt < NNB){
            float acc = 0.0f;
            #pragma unroll
            for (int h2 = 0; h2 < HEADS; h2++) acc += S.cwh[tt][h2]*c_comb[h2];
            S.wj[tt] = acc;
        }
        if (tt >= 64 && tt < 64+HEADS){
            int h2 = tt - 64;
            float m = -1e30f;
            for (int j = 0; j < NNB; j++) m = fmaxf(m, S.lg[j][h2]);
            float ll = 0.0f;
            for (int j = 0; j < NNB; j++){ float pr = expf(S.lg[j][h2]-m); S.at[j][h2] = pr; ll += pr; }
            float rl = 1.0f/ll;
            for (int j = 0; j < NNB; j++) S.at[j][h2] *= rl;
        }
        __syncthreads();

        // coordinate update
        if (tt < 3){
            float acc = 0.0f;
            for (int j = 0; j < NNB; j++) acc += S.wj[j]*S.reln[j][tt];
            cout[(b*NV+i)*3+tt] = cin[(b*NV+i)*3+tt] + acc;
        }

        // attn @ V -> LDS As[local row]
        int hv = tt >> 5;
        float ax = 0.f, ay = 0.f, az = 0.f, aw = 0.f;
        for (int j = 0; j < NNB; j++){
            float a = S.at[j][hv];
            uint2 v = *(const uint2*)&kvh[(size_t)(b*NV+S.jid[j])*2048 + 1024 + tt*4];
            ax += a*bflo(v.x); ay += a*bfhi(v.x); az += a*bflo(v.y); aw += a*bfhi(v.y);
        }
        *(float4*)&As[p*2+half][tt*4] = make_float4(ax, ay, az, aw);
        __syncthreads();   // protect sb reuse by next pass
    }

    // ================= tail: out-proj + residual + LN2 + FFN (t<256) =================
    if (t < 256){
        int r = t >> 6, c = t & 63;      // wave = row
        const float* arow = As[r];
        float acc = 0.0f;
        #pragma unroll 8
        for (int k = 0; k < 1024; k++)
            acc += arow[k]*out_w[k*DIM + c];

        float v = h[(size_t)(r0+r)*DIM + c] + acc + out_b[c];
        hs[r][c] = v;
        float s = v;
        #pragma unroll
        for (int m = 32; m >= 1; m >>= 1) s += __shfl_xor(s, m, 64);
        float mu = s*(1.0f/64.0f);
        float d = v - mu;
        float vv = d*d;
        #pragma unroll
        for (int m = 32; m >= 1; m >>= 1) vv += __shfl_xor(vv, m, 64);
        ys[r][c] = d / sqrtf(vv*(1.0f/64.0f) + 1e-5f) * g2[c] + b2[c];
    }
    __syncthreads();

    if (t < 256){
        float u0 = fb1[t], u1 = u0, u2 = u0, u3 = u0;
        #pragma unroll 8
        for (int k = 0; k < 64; k++){
            float w = fw1[k*256 + t];
            u0 += ys[0][k]*w; u1 += ys[1][k]*w; u2 += ys[2][k]*w; u3 += ys[3][k]*w;
        }
        us[0][t] = gelu_t(u0); us[1][t] = gelu_t(u1); us[2][t] = gelu_t(u2); us[3][t] = gelu_t(u3);
    }
    __syncthreads();

    if (t < 256){
        int r = t >> 6, c = t & 63;
        float f2 = fb2[c];
        #pragma unroll 8
        for (int k = 0; k < 256; k++) f2 += us[r][k]*fw2[k*DIM + c];
        h[(size_t)(r0+r)*DIM + c] = hs[r][c] + f2;
    }
}

// ---------------------------------------------------------------- classifier + softmax
__global__ __launch_bounds__(64) void k_cls(const float* __restrict__ h,
                                            const float* __restrict__ cls_w,
                                            const float* __restrict__ cls_b,
                                            float* __restrict__ out){
    int row = blockIdx.x;
    int t = threadIdx.x;
    __shared__ float lg[20];
    if (t < 20){
        float acc = cls_b[t];
        #pragma unroll 8
        for (int k = 0; k < 64; k++) acc += h[row*DIM+k]*cls_w[k*20+t];
        lg[t] = acc;
    }
    __syncthreads();
    if (t < 20){
        float m = -1e30f;
        for (int c = 0; c < 20; c++) m = fmaxf(m, lg[c]);
        float l = 0.0f;
        for (int c = 0; c < 20; c++) l += expf(lg[c]-m);
        out[row*20+t] = expf(lg[t]-m)/l;
    }
}

extern "C" void kernel_launch(void* const* d_in, const int* in_sizes, int n_in,
                              void* d_out, int out_size, void* d_ws, size_t ws_size,
                              hipStream_t stream) {
    const float* feats = (const float*)d_in[0];
    const float* coors = (const float*)d_in[1];
    const float* edges = (const float*)d_in[2];
    // d_in[3] = mask (all true) — unused
    const float* fe_w  = (const float*)d_in[4];
    const float* fe_b  = (const float*)d_in[5];
    const float* ln1_g = (const float*)d_in[6];
    const float* ln1_b = (const float*)d_in[7];
    const float* qkv_w = (const float*)d_in[8];
    const float* out_w = (const float*)d_in[9];
    const float* out_b = (const float*)d_in[10];
    const float* ew1   = (const float*)d_in[11];
    const float* eb1   = (const float*)d_in[12];
    const float* ew2   = (const float*)d_in[13];
    const float* eb2   = (const float*)d_in[14];
    const float* cw1   = (const float*)d_in[15];
    const float* cb1   = (const float*)d_in[16];
    const float* cw2   = (const float*)d_in[17];
    const float* cb2   = (const float*)d_in[18];
    const float* c_scale = (const float*)d_in[19];
    const float* c_comb  = (const float*)d_in[20];
    const float* ln2_g = (const float*)d_in[21];
    const float* ln2_b = (const float*)d_in[22];
    const float* fw1   = (const float*)d_in[23];
    const float* fb1   = (const float*)d_in[24];
    const float* fw2   = (const float*)d_in[25];
    const float* fb2   = (const float*)d_in[26];
    const float* cls_w = (const float*)d_in[27];
    const float* cls_b = (const float*)d_in[28];

    float* ws   = (float*)d_ws;
    float* h    = ws;                                  // 1024*64
    float* cA   = h + BN*DIM;                          // 1024*3
    float* cB   = cA + BN*3;                           // 1024*3
    float* qf   = cB + BN*3;                           // 1024*1024 f32 (4 MB): Q
    unsigned short* kvh = (unsigned short*)(qf + (size_t)BN*INNER); // 1024*2048 bf16 (4 MB): K|V
    int*   idx  = (int*)(kvh + (size_t)BN*2048);       // 1024*30

    k_embed<<<BN, 64, 0, stream>>>(feats, coors, fe_w, fe_b, h, cA);

    float* cin = cA; float* cout = cB;
    for (int l = 0; l < 8; l++){
        k_head<<<640, 256, 0, stream>>>(h, ln1_g + l*DIM, ln1_b + l*DIM,
                                        qkv_w + (size_t)l*DIM*3*INNER,
                                        qf, kvh, cin, idx);
        k_attn4<<<BN/4, 512, 0, stream>>>(qf, kvh, idx, cin, cout, edges, h,
                                          ew1 + l*9*18,  eb1 + l*18,
                                          ew2 + l*18*8,  eb2 + l*8,
                                          cw1 + l*8*64,  cb1 + l*64,
                                          cw2 + l*64*8,  cb2 + l*8,
                                          c_scale + l,   c_comb + l*8,
                                          out_w + (size_t)l*INNER*DIM, out_b + l*DIM,
                                          ln2_g + l*DIM, ln2_b + l*DIM,
                                          fw1 + (size_t)l*DIM*256, fb1 + l*256,
                                          fw2 + (size_t)l*256*DIM, fb2 + l*64);
        float* tmp = cin; cin = cout; cout = tmp;
    }

    k_cls<<<BN, 64, 0, stream>>>(h, cls_w, cls_b, (float*)d_out);
}

// Round 9
// 605.785 us; speedup vs baseline: 10.3663x; 1.5907x over previous
//
#include <hip/hip_runtime.h>
#include <hip/hip_bf16.h>

#define NV    512           // N nodes
#define BN    1024          // B*N rows
#define NNB   30            // neighbors
#define DIM   64
#define HEADS 8
#define DH    128
#define INNER 1024          // HEADS*DH

// jax.nn.gelu default: approximate=True (tanh form)
__device__ __forceinline__ float gelu_t(float x){
    float x3 = x*x*x;
    return 0.5f*x*(1.0f + tanhf(0.7978845608028654f*(x + 0.044715f*x3)));
}
__device__ __forceinline__ unsigned short f2bf(float x){
    __hip_bfloat16 h = __float2bfloat16(x);           // RNE
    return __builtin_bit_cast(unsigned short, h);
}
__device__ __forceinline__ float bflo(unsigned u){ return __uint_as_float(u << 16); }
__device__ __forceinline__ float bfhi(unsigned u){ return __uint_as_float(u & 0xffff0000u); }

// ---------------------------------------------------------------- embed
__global__ __launch_bounds__(64) void k_embed(const float* __restrict__ feats,
                                              const float* __restrict__ coors,
                                              const float* __restrict__ fe_w,
                                              const float* __restrict__ fe_b,
                                              float* __restrict__ h,
                                              float* __restrict__ coorsA){
    int row = blockIdx.x;
    int t = threadIdx.x;
    __shared__ float x[6];
    if (t < 3){
        float f = feats[row*3+t];
        x[t]   = sinf(f);
        x[t+3] = cosf(f);
        coorsA[row*3+t] = coors[row*3+t];
    }
    __syncthreads();
    float acc = fe_b[t];
    #pragma unroll
    for (int k = 0; k < 6; k++) acc += x[k]*fe_w[k*DIM+t];
    h[row*DIM+t] = fmaxf(acc, 0.0f);
}

// ---------------------------------------------------------------- fused head: LN1+qkv GEMM (blocks 0..383) | topk (blocks 384..639)
__global__ __launch_bounds__(256) void k_head(const float* __restrict__ h,
                                              const float* __restrict__ g,
                                              const float* __restrict__ be,
                                              const float* __restrict__ w,     // (64,3072)
                                              float* __restrict__ qf,
                                              unsigned short* __restrict__ kvh,
                                              const float* __restrict__ coors,
                                              int* __restrict__ idx){
    __shared__ float At[64][68];
    __shared__ float Wt[64][132];
    int t = threadIdx.x;
    int wv = t >> 6, lane = t & 63;

    if (blockIdx.x < 384){
        int rt = blockIdx.x / 24, ct = blockIdx.x % 24;
        int row0 = rt*64, col0 = ct*128;

        float gk = g[lane], bk = be[lane];
        #pragma unroll 4
        for (int rr = 0; rr < 16; rr++){
            int r = wv*16 + rr;
            float v = h[(row0+r)*DIM + lane];
            float s = v;
            #pragma unroll
            for (int m = 32; m >= 1; m >>= 1) s += __shfl_xor(s, m, 64);
            float mu = s*(1.0f/64.0f);
            float d = v - mu;
            float vv = d*d;
            #pragma unroll
            for (int m = 32; m >= 1; m >>= 1) vv += __shfl_xor(vv, m, 64);
            At[lane][r] = d / sqrtf(vv*(1.0f/64.0f) + 1e-5f) * gk + bk;
        }
        const float* wg = w + col0;
        #pragma unroll
        for (int i = t*4; i < 64*128; i += 1024){
            int k = i >> 7, c = i & 127;
            *(float4*)&Wt[k][c] = *(const float4*)&wg[k*3072 + c];
        }
        __syncthreads();

        int ty = t >> 4, tx = t & 15;
        float acc[4][8];
        #pragma unroll
        for (int i = 0; i < 4; i++)
            #pragma unroll
            for (int j = 0; j < 8; j++) acc[i][j] = 0.0f;

        #pragma unroll 2
        for (int k = 0; k < 64; k++){
            float4 a  = *(const float4*)&At[k][ty*4];
            float4 w0 = *(const float4*)&Wt[k][tx*4];
            float4 w1 = *(const float4*)&Wt[k][64 + tx*4];
            float av[4]  = {a.x, a.y, a.z, a.w};
            float wv8[8] = {w0.x, w0.y, w0.z, w0.w, w1.x, w1.y, w1.z, w1.w};
            #pragma unroll
            for (int i = 0; i < 4; i++)
                #pragma unroll
                for (int j = 0; j < 8; j++) acc[i][j] += av[i]*wv8[j];
        }

        if (ct < 8){
            #pragma unroll
            for (int i = 0; i < 4; i++){
                int r = row0 + ty*4 + i;
                float* dst = &qf[(size_t)r*INNER + col0];
                *(float4*)&dst[tx*4]      = make_float4(acc[i][0], acc[i][1], acc[i][2], acc[i][3]);
                *(float4*)&dst[64 + tx*4] = make_float4(acc[i][4], acc[i][5], acc[i][6], acc[i][7]);
            }
        } else {
            int kvcol0 = col0 - 1024;
            #pragma unroll
            for (int i = 0; i < 4; i++){
                int r = row0 + ty*4 + i;
                unsigned short* dst = &kvh[(size_t)r*2048 + kvcol0];
                ushort4 p0 = { f2bf(acc[i][0]), f2bf(acc[i][1]), f2bf(acc[i][2]), f2bf(acc[i][3]) };
                ushort4 p1 = { f2bf(acc[i][4]), f2bf(acc[i][5]), f2bf(acc[i][6]), f2bf(acc[i][7]) };
                *(ushort4*)&dst[tx*4]      = p0;
                *(ushort4*)&dst[64 + tx*4] = p1;
            }
        }
    } else {
        int row = (blockIdx.x - 384)*4 + wv;
        int b = row >> 9;
        const float* cbp = coors + (size_t)b*NV*3;
        float cx = coors[row*3+0], cy = coors[row*3+1], cz = coors[row*3+2];
        float d2[8];
        int jb = lane*8;
        #pragma unroll
        for (int u = 0; u < 8; u++){
            float dx = cx - cbp[(jb+u)*3+0];
            float dy = cy - cbp[(jb+u)*3+1];
            float dz = cz - cbp[(jb+u)*3+2];
            d2[u] = dx*dx + dy*dy + dz*dz;
        }
        for (int sel = 0; sel < NNB; sel++){
            float bv = d2[0]; int bu = 0;
            #pragma unroll
            for (int u = 1; u < 8; u++) if (d2[u] < bv){ bv = d2[u]; bu = u; }
            int bj = jb + bu;
            #pragma unroll
            for (int m = 32; m >= 1; m >>= 1){
                float ov = __shfl_xor(bv, m, 64);
                int   oj = __shfl_xor(bj, m, 64);
                if (ov < bv || (ov == bv && oj < bj)){ bv = ov; bj = oj; }
            }
            if (lane == 0) idx[row*NNB + sel] = bj;
            #pragma unroll
            for (int u = 0; u < 8; u++) if (jb + u == bj) d2[u] = 1e30f;
        }
    }
}

// ---------------------------------------------------------------- full layer core: attention + out-proj + LN2 + FFN
// 1 row per block, 1024 blocks, 256 threads. aout stays in LDS.
__global__ __launch_bounds__(256) void k_layer(const float* __restrict__ qf,
                                               const unsigned short* __restrict__ kvh,
                                               const int*   __restrict__ idx,
                                               const float* __restrict__ cin,
                                               float*       __restrict__ cout,
                                               const float* __restrict__ edges,
                                               float*       __restrict__ h,
                                               const float* __restrict__ ew1, const float* __restrict__ eb1,
                                               const float* __restrict__ ew2, const float* __restrict__ eb2,
                                               const float* __restrict__ cw1, const float* __restrict__ cb1,
                                               const float* __restrict__ cw2, const float* __restrict__ cb2,
                                               const float* __restrict__ c_scale, const float* __restrict__ c_comb,
                                               const float* __restrict__ out_w,  const float* __restrict__ out_b,
                                               const float* __restrict__ g2, const float* __restrict__ b2,
                                               const float* __restrict__ fw1, const float* __restrict__ fb1,
                                               const float* __restrict__ fw2, const float* __restrict__ fb2){
    int row = blockIdx.x;
    int b = row >> 9, i = row & (NV-1);
    int t = threadIdx.x;
    int wave = t >> 6, lane = t & 63;

    __shared__ float qk[NNB][HEADS];   // raw logits
    __shared__ float lg[NNB][HEADS];   // conditioned logits
    __shared__ float t18[NNB][18];
    __shared__ float t64s[NNB][64];
    __shared__ float cwh[NNB][HEADS];
    __shared__ float attn[NNB][HEADS];
    __shared__ float ej[NNB];
    __shared__ float reln[NNB][3];
    __shared__ float wj[NNB];
    __shared__ int   jid[NNB];
    __shared__ float As[INNER];        // attn@V output (4 KB)
    __shared__ float red[256];
    __shared__ float hsr[DIM];
    __shared__ float ys[DIM];
    __shared__ float us[256];

    if (t < NNB) jid[t] = idx[row*NNB + t];
    __syncthreads();

    // q in registers: lane owns dims [lane*16, lane*16+16) -> head = lane>>3
    float qreg[16];
    {
        const float4* qp = (const float4*)&qf[(size_t)row*INNER + lane*16];
        #pragma unroll
        for (int e = 0; e < 4; e++){
            float4 v = qp[e];
            qreg[e*4+0] = v.x; qreg[e*4+1] = v.y; qreg[e*4+2] = v.z; qreg[e*4+3] = v.w;
        }
    }

    if (t < NNB){
        int jj = jid[t];
        ej[t] = edges[(size_t)(b*NV+i)*NV + jj];
        float rx = cin[(b*NV+i)*3+0] - cin[(b*NV+jj)*3+0];
        float ry = cin[(b*NV+i)*3+1] - cin[(b*NV+jj)*3+1];
        float rz = cin[(b*NV+i)*3+2] - cin[(b*NV+jj)*3+2];
        float s = rx*rx + ry*ry + rz*rz;
        float den = fmaxf(sqrtf(s == 0.0f ? 1.0f : s), 1e-8f);
        float cs = c_scale[0];
        reln[t][0] = rx/den*cs;
        reln[t][1] = ry/den*cs;
        reln[t][2] = rz/den*cs;
    }

    // ---- qk logits: wave-per-neighbor, q f32 regs x K bf16
    int part = lane & 7, hh = lane >> 3;
    #pragma unroll 2
    for (int j = wave; j < NNB; j += 4){
        int jj = jid[j];
        const uint4* kp = (const uint4*)&kvh[(size_t)(b*NV+jj)*2048 + lane*16];
        uint4 u0 = kp[0];
        uint4 u1 = kp[1];
        float acc = qreg[0]*bflo(u0.x) + qreg[1]*bfhi(u0.x)
                  + qreg[2]*bflo(u0.y) + qreg[3]*bfhi(u0.y)
                  + qreg[4]*bflo(u0.z) + qreg[5]*bfhi(u0.z)
                  + qreg[6]*bflo(u0.w) + qreg[7]*bfhi(u0.w);
        acc += qreg[8]*bflo(u1.x)  + qreg[9]*bfhi(u1.x)
             + qreg[10]*bflo(u1.y) + qreg[11]*bfhi(u1.y)
             + qreg[12]*bflo(u1.z) + qreg[13]*bfhi(u1.z)
             + qreg[14]*bflo(u1.w) + qreg[15]*bfhi(u1.w);
        acc += __shfl_xor(acc, 1, 64);
        acc += __shfl_xor(acc, 2, 64);
        acc += __shfl_xor(acc, 4, 64);
        if (part == 0) qk[j][hh] = acc * 0.08838834764831845f;  // 1/sqrt(128)
    }
    __syncthreads();

    // ---- edge MLP layer 1: (qk||e) (9) -> 18, gelu
    for (int id = t; id < NNB*18; id += 256){
        int j = id/18, u = id%18;
        float acc = eb1[u];
        #pragma unroll
        for (int k = 0; k < 8; k++) acc += qk[j][k]*ew1[k*18+u];
        acc += ej[j]*ew1[8*18+u];
        t18[j][u] = gelu_t(acc);
    }
    __syncthreads();
    // ---- edge MLP layer 2: 18 -> 8
    if (t < NNB*HEADS){
        int j = t/HEADS, h2 = t%HEADS;
        float acc = eb2[h2];
        #pragma unroll
        for (int k = 0; k < 18; k++) acc += t18[j][k]*ew2[k*HEADS+h2];
        lg[j][h2] = acc;
    }
    __syncthreads();

    // ---- coord MLP: gelu(lg) (8) -> 64 gelu -> 8
    for (int id = t; id < NNB*64; id += 256){
        int j = id/64, u = id%64;
        float acc = cb1[u];
        #pragma unroll
        for (int k = 0; k < 8; k++) acc += gelu_t(lg[j][k])*cw1[k*64+u];
        t64s[j][u] = gelu_t(acc);
    }
    __syncthreads();
    if (t < NNB*HEADS){
        int j = t/HEADS, h2 = t%HEADS;
        float acc = cb2[h2];
        #pragma unroll 8
        for (int k = 0; k < 64; k++) acc += t64s[j][k]*cw2[k*HEADS+h2];
        cwh[j][h2] = acc;
    }
    __syncthreads();

    // ---- per-neighbor coord weight, per-head softmax
    if (t < NNB){
        float acc = 0.0f;
        #pragma unroll
        for (int h2 = 0; h2 < HEADS; h2++) acc += cwh[t][h2]*c_comb[h2];
        wj[t] = acc;
    }
    if (t >= 64 && t < 64+HEADS){
        int h2 = t - 64;
        float m = -1e30f;
        for (int j = 0; j < NNB; j++) m = fmaxf(m, lg[j][h2]);
        float ll = 0.0f;
        for (int j = 0; j < NNB; j++){ float pr = expf(lg[j][h2]-m); attn[j][h2] = pr; ll += pr; }
        float rl = 1.0f/ll;
        for (int j = 0; j < NNB; j++) attn[j][h2] *= rl;
    }
    __syncthreads();

    // ---- coordinate update
    if (t < 3){
        float acc = 0.0f;
        for (int j = 0; j < NNB; j++) acc += wj[j]*reln[j][t];
        cout[(b*NV+i)*3+t] = cin[(b*NV+i)*3+t] + acc;
    }

    // ---- attn @ V (bf16) -> LDS As
    int hv = t >> 5;
    float ax = 0.f, ay = 0.f, az = 0.f, aw = 0.f;
    for (int j = 0; j < NNB; j++){
        float a = attn[j][hv];
        uint2 v = *(const uint2*)&kvh[(size_t)(b*NV+jid[j])*2048 + 1024 + t*4];
        ax += a*bflo(v.x); ay += a*bfhi(v.x); az += a*bflo(v.y); aw += a*bfhi(v.y);
    }
    *(float4*)&As[t*4] = make_float4(ax, ay, az, aw);
    __syncthreads();

    // ---- out-proj (1024 -> 64): 4 partials per output dim
    int d = t & 63, prt = t >> 6;
    {
        float acc = 0.0f;
        const float* as = &As[prt*256];
        const float* wp = &out_w[(size_t)prt*256*DIM + d];
        #pragma unroll 8
        for (int k = 0; k < 256; k++) acc += as[k]*wp[k*DIM];
        red[t] = acc;
    }
    __syncthreads();
    if (t < 64){
        float r = red[t] + red[t+64] + red[t+128] + red[t+192];
        float v = h[(size_t)row*DIM + t] + r + out_b[t];
        hsr[t] = v;
        // LN2 (t<64 is one wave)
        float s = v;
        #pragma unroll
        for (int m = 32; m >= 1; m >>= 1) s += __shfl_xor(s, m, 64);
        float mu = s*(1.0f/64.0f);
        float dd = v - mu;
        float vv = dd*dd;
        #pragma unroll
        for (int m = 32; m >= 1; m >>= 1) vv += __shfl_xor(vv, m, 64);
        ys[t] = dd / sqrtf(vv*(1.0f/64.0f) + 1e-5f) * g2[t] + b2[t];
    }
    __syncthreads();

    // ---- FFN1: 64 -> 256, gelu
    {
        float u = fb1[t];
        #pragma unroll 8
        for (int k = 0; k < 64; k++) u += ys[k]*fw1[k*256 + t];
        us[t] = gelu_t(u);
    }
    __syncthreads();

    // ---- FFN2: 256 -> 64, + residual
    if (t < 64){
        float f2 = fb2[t];
        #pragma unroll 8
        for (int k = 0; k < 256; k++) f2 += us[k]*fw2[k*DIM + t];
        h[(size_t)row*DIM + t] = hsr[t] + f2;
    }
}

// ---------------------------------------------------------------- classifier + softmax
__global__ __launch_bounds__(64) void k_cls(const float* __restrict__ h,
                                            const float* __restrict__ cls_w,
                                            const float* __restrict__ cls_b,
                                            float* __restrict__ out){
    int row = blockIdx.x;
    int t = threadIdx.x;
    __shared__ float lg[20];
    if (t < 20){
        float acc = cls_b[t];
        #pragma unroll 8
        for (int k = 0; k < 64; k++) acc += h[row*DIM+k]*cls_w[k*20+t];
        lg[t] = acc;
    }
    __syncthreads();
    if (t < 20){
        float m = -1e30f;
        for (int c = 0; c < 20; c++) m = fmaxf(m, lg[c]);
        float l = 0.0f;
        for (int c = 0; c < 20; c++) l += expf(lg[c]-m);
        out[row*20+t] = expf(lg[t]-m)/l;
    }
}

extern "C" void kernel_launch(void* const* d_in, const int* in_sizes, int n_in,
                              void* d_out, int out_size, void* d_ws, size_t ws_size,
                              hipStream_t stream) {
    const float* feats = (const float*)d_in[0];
    const float* coors = (const float*)d_in[1];
    const float* edges = (const float*)d_in[2];
    // d_in[3] = mask (all true) — unused
    const float* fe_w  = (const float*)d_in[4];
    const float* fe_b  = (const float*)d_in[5];
    const float* ln1_g = (const float*)d_in[6];
    const float* ln1_b = (const float*)d_in[7];
    const float* qkv_w = (const float*)d_in[8];
    const float* out_w = (const float*)d_in[9];
    const float* out_b = (const float*)d_in[10];
    const float* ew1   = (const float*)d_in[11];
    const float* eb1   = (const float*)d_in[12];
    const float* ew2   = (const float*)d_in[13];
    const float* eb2   = (const float*)d_in[14];
    const float* cw1   = (const float*)d_in[15];
    const float* cb1   = (const float*)d_in[16];
    const float* cw2   = (const float*)d_in[17];
    const float* cb2   = (const float*)d_in[18];
    const float* c_scale = (const float*)d_in[19];
    const float* c_comb  = (const float*)d_in[20];
    const float* ln2_g = (const float*)d_in[21];
    const float* ln2_b = (const float*)d_in[22];
    const float* fw1   = (const float*)d_in[23];
    const float* fb1   = (const float*)d_in[24];
    const float* fw2   = (const float*)d_in[25];
    const float* fb2   = (const float*)d_in[26];
    const float* cls_w = (const float*)d_in[27];
    const float* cls_b = (const float*)d_in[28];

    float* ws   = (float*)d_ws;
    float* h    = ws;                                  // 1024*64
    float* cA   = h + BN*DIM;                          // 1024*3
    float* cB   = cA + BN*3;                           // 1024*3
    float* qf   = cB + BN*3;                           // 1024*1024 f32 (4 MB): Q
    unsigned short* kvh = (unsigned short*)(qf + (size_t)BN*INNER); // 1024*2048 bf16 (4 MB): K|V
    int*   idx  = (int*)(kvh + (size_t)BN*2048);       // 1024*30

    k_embed<<<BN, 64, 0, stream>>>(feats, coors, fe_w, fe_b, h, cA);

    float* cin = cA; float* cout = cB;
    for (int l = 0; l < 8; l++){
        k_head<<<640, 256, 0, stream>>>(h, ln1_g + l*DIM, ln1_b + l*DIM,
                                        qkv_w + (size_t)l*DIM*3*INNER,
                                        qf, kvh, cin, idx);
        k_layer<<<BN, 256, 0, stream>>>(qf, kvh, idx, cin, cout, edges, h,
                                        ew1 + l*9*18,  eb1 + l*18,
                                        ew2 + l*18*8,  eb2 + l*8,
                                        cw1 + l*8*64,  cb1 + l*64,
                                        cw2 + l*64*8,  cb2 + l*8,
                                        c_scale + l,   c_comb + l*8,
                                        out_w + (size_t)l*INNER*DIM, out_b + l*DIM,
                                        ln2_g + l*DIM, ln2_b + l*DIM,
                                        fw1 + (size_t)l*DIM*256, fb1 + l*256,
                                        fw2 + (size_t)l*256*DIM, fb2 + l*64);
        float* tmp = cin; cin = cout; cout = tmp;
    }

    k_cls<<<BN, 64, 0, stream>>>(h, cls_w, cls_b, (float*)d_out);
}

// Round 10
// 518.284 us; speedup vs baseline: 12.1164x; 1.1688x over previous
//
#include <hip/hip_runtime.h>
#include <hip/hip_bf16.h>

#define NV    512           // N nodes
#define BN    1024          // B*N rows
#define NNB   30            // neighbors
#define DIM   64
#define HEADS 8
#define DH    128
#define INNER 1024          // HEADS*DH

// jax.nn.gelu default: approximate=True (tanh form)
__device__ __forceinline__ float gelu_t(float x){
    float x3 = x*x*x;
    return 0.5f*x*(1.0f + tanhf(0.7978845608028654f*(x + 0.044715f*x3)));
}
__device__ __forceinline__ unsigned short f2bf(float x){
    __hip_bfloat16 h = __float2bfloat16(x);           // RNE
    return __builtin_bit_cast(unsigned short, h);
}
__device__ __forceinline__ float bflo(unsigned u){ return __uint_as_float(u << 16); }
__device__ __forceinline__ float bfhi(unsigned u){ return __uint_as_float(u & 0xffff0000u); }

// ---------------------------------------------------------------- embed
__global__ __launch_bounds__(64) void k_embed(const float* __restrict__ feats,
                                              const float* __restrict__ coors,
                                              const float* __restrict__ fe_w,
                                              const float* __restrict__ fe_b,
                                              float* __restrict__ h,
                                              float* __restrict__ coorsA){
    int row = blockIdx.x;
    int t = threadIdx.x;
    __shared__ float x[6];
    if (t < 3){
        float f = feats[row*3+t];
        x[t]   = sinf(f);
        x[t+3] = cosf(f);
        coorsA[row*3+t] = coors[row*3+t];
    }
    __syncthreads();
    float acc = fe_b[t];
    #pragma unroll
    for (int k = 0; k < 6; k++) acc += x[k]*fe_w[k*DIM+t];
    h[row*DIM+t] = fmaxf(acc, 0.0f);
}

// ---------------------------------------------------------------- fused head: LN1+qkv GEMM (blocks 0..383) | topk (blocks 384..639)
__global__ __launch_bounds__(256) void k_head(const float* __restrict__ h,
                                              const float* __restrict__ g,
                                              const float* __restrict__ be,
                                              const float* __restrict__ w,     // (64,3072)
                                              float* __restrict__ qf,
                                              unsigned short* __restrict__ kvh,
                                              const float* __restrict__ coors,
                                              int* __restrict__ idx){
    __shared__ float At[64][68];
    __shared__ float Wt[64][132];
    int t = threadIdx.x;
    int wv = t >> 6, lane = t & 63;

    if (blockIdx.x < 384){
        int rt = blockIdx.x / 24, ct = blockIdx.x % 24;
        int row0 = rt*64, col0 = ct*128;

        float gk = g[lane], bk = be[lane];
        #pragma unroll 4
        for (int rr = 0; rr < 16; rr++){
            int r = wv*16 + rr;
            float v = h[(row0+r)*DIM + lane];
            float s = v;
            #pragma unroll
            for (int m = 32; m >= 1; m >>= 1) s += __shfl_xor(s, m, 64);
            float mu = s*(1.0f/64.0f);
            float d = v - mu;
            float vv = d*d;
            #pragma unroll
            for (int m = 32; m >= 1; m >>= 1) vv += __shfl_xor(vv, m, 64);
            At[lane][r] = d / sqrtf(vv*(1.0f/64.0f) + 1e-5f) * gk + bk;
        }
        const float* wg = w + col0;
        #pragma unroll
        for (int i = t*4; i < 64*128; i += 1024){
            int k = i >> 7, c = i & 127;
            *(float4*)&Wt[k][c] = *(const float4*)&wg[k*3072 + c];
        }
        __syncthreads();

        int ty = t >> 4, tx = t & 15;
        float acc[4][8];
        #pragma unroll
        for (int i = 0; i < 4; i++)
            #pragma unroll
            for (int j = 0; j < 8; j++) acc[i][j] = 0.0f;

        #pragma unroll 2
        for (int k = 0; k < 64; k++){
            float4 a  = *(const float4*)&At[k][ty*4];
            float4 w0 = *(const float4*)&Wt[k][tx*4];
            float4 w1 = *(const float4*)&Wt[k][64 + tx*4];
            float av[4]  = {a.x, a.y, a.z, a.w};
            float wv8[8] = {w0.x, w0.y, w0.z, w0.w, w1.x, w1.y, w1.z, w1.w};
            #pragma unroll
            for (int i = 0; i < 4; i++)
                #pragma unroll
                for (int j = 0; j < 8; j++) acc[i][j] += av[i]*wv8[j];
        }

        if (ct < 8){
            #pragma unroll
            for (int i = 0; i < 4; i++){
                int r = row0 + ty*4 + i;
                float* dst = &qf[(size_t)r*INNER + col0];
                *(float4*)&dst[tx*4]      = make_float4(acc[i][0], acc[i][1], acc[i][2], acc[i][3]);
                *(float4*)&dst[64 + tx*4] = make_float4(acc[i][4], acc[i][5], acc[i][6], acc[i][7]);
            }
        } else {
            int kvcol0 = col0 - 1024;
            #pragma unroll
            for (int i = 0; i < 4; i++){
                int r = row0 + ty*4 + i;
                unsigned short* dst = &kvh[(size_t)r*2048 + kvcol0];
                ushort4 p0 = { f2bf(acc[i][0]), f2bf(acc[i][1]), f2bf(acc[i][2]), f2bf(acc[i][3]) };
                ushort4 p1 = { f2bf(acc[i][4]), f2bf(acc[i][5]), f2bf(acc[i][6]), f2bf(acc[i][7]) };
                *(ushort4*)&dst[tx*4]      = p0;
                *(ushort4*)&dst[64 + tx*4] = p1;
            }
        }
    } else {
        int row = (blockIdx.x - 384)*4 + wv;
        int b = row >> 9;
        const float* cbp = coors + (size_t)b*NV*3;
        float cx = coors[row*3+0], cy = coors[row*3+1], cz = coors[row*3+2];
        float d2[8];
        int jb = lane*8;
        #pragma unroll
        for (int u = 0; u < 8; u++){
            float dx = cx - cbp[(jb+u)*3+0];
            float dy = cy - cbp[(jb+u)*3+1];
            float dz = cz - cbp[(jb+u)*3+2];
            d2[u] = dx*dx + dy*dy + dz*dz;
        }
        for (int sel = 0; sel < NNB; sel++){
            float bv = d2[0]; int bu = 0;
            #pragma unroll
            for (int u = 1; u < 8; u++) if (d2[u] < bv){ bv = d2[u]; bu = u; }
            int bj = jb + bu;
            #pragma unroll
            for (int m = 32; m >= 1; m >>= 1){
                float ov = __shfl_xor(bv, m, 64);
                int   oj = __shfl_xor(bj, m, 64);
                if (ov < bv || (ov == bv && oj < bj)){ bv = ov; bj = oj; }
            }
            if (lane == 0) idx[row*NNB + sel] = bj;
            #pragma unroll
            for (int u = 0; u < 8; u++) if (jb + u == bj) d2[u] = 1e30f;
        }
    }
}

// ---------------------------------------------------------------- full layer core: attention + out-proj + LN2 + FFN
// 1 row per block, 1024 blocks, 256 threads.
__global__ __launch_bounds__(256) void k_layer(const float* __restrict__ qf,
                                               const unsigned short* __restrict__ kvh,
                                               const int*   __restrict__ idx,
                                               const float* __restrict__ cin,
                                               float*       __restrict__ cout,
                                               const float* __restrict__ edges,
                                               float* __restrict__ h,
                                               const float* __restrict__ ew1, const float* __restrict__ eb1,
                                               const float* __restrict__ ew2, const float* __restrict__ eb2,
                                               const float* __restrict__ cw1, const float* __restrict__ cb1,
                                               const float* __restrict__ cw2, const float* __restrict__ cb2,
                                               const float* __restrict__ c_scale, const float* __restrict__ c_comb,
                                               const float* __restrict__ out_w,  const float* __restrict__ out_b,
                                               const float* __restrict__ g2, const float* __restrict__ b2,
                                               const float* __restrict__ fw1, const float* __restrict__ fb1,
                                               const float* __restrict__ fw2, const float* __restrict__ fb2){
    int row = blockIdx.x;
    int b = row >> 9, i = row & (NV-1);
    int t = threadIdx.x;
    int wave = t >> 6, lane = t & 63;

    __shared__ float qk[NNB][HEADS];   // raw logits; later reused for gelu(lg)
    __shared__ float lg[NNB][HEADS];   // conditioned logits
    __shared__ float t18[NNB][18];
    __shared__ float t64s[NNB][65];    // +1 pad: kills 8-way read conflict in coord MLP2
    __shared__ float cwh[NNB][HEADS];
    __shared__ float attn[NNB][HEADS];
    __shared__ float ej[NNB];
    __shared__ float reln[NNB][3];
    __shared__ float wj[NNB];
    __shared__ int   jid[NNB];
    __shared__ float As[INNER];        // attn@V output (4 KB)
    __shared__ float red[256];
    __shared__ float hsr[DIM];
    __shared__ float ys[DIM];
    __shared__ float us[256];

    if (t < NNB) jid[t] = idx[row*NNB + t];
    __syncthreads();

    // q in registers: lane owns dims [lane*16, lane*16+16) -> head = lane>>3
    float qreg[16];
    {
        const float4* qp = (const float4*)&qf[(size_t)row*INNER + lane*16];
        #pragma unroll
        for (int e = 0; e < 4; e++){
            float4 v = qp[e];
            qreg[e*4+0] = v.x; qreg[e*4+1] = v.y; qreg[e*4+2] = v.z; qreg[e*4+3] = v.w;
        }
    }

    if (t < NNB){
        int jj = jid[t];
        ej[t] = edges[(size_t)(b*NV+i)*NV + jj];
        float rx = cin[(b*NV+i)*3+0] - cin[(b*NV+jj)*3+0];
        float ry = cin[(b*NV+i)*3+1] - cin[(b*NV+jj)*3+1];
        float rz = cin[(b*NV+i)*3+2] - cin[(b*NV+jj)*3+2];
        float s = rx*rx + ry*ry + rz*rz;
        float den = fmaxf(sqrtf(s == 0.0f ? 1.0f : s), 1e-8f);
        float cs = c_scale[0];
        reln[t][0] = rx/den*cs;
        reln[t][1] = ry/den*cs;
        reln[t][2] = rz/den*cs;
    }

    // ---- qk logits: wave-per-neighbor, q f32 regs x K bf16
    int part = lane & 7, hh = lane >> 3;
    #pragma unroll 2
    for (int j = wave; j < NNB; j += 4){
        int jj = jid[j];
        const uint4* kp = (const uint4*)&kvh[(size_t)(b*NV+jj)*2048 + lane*16];
        uint4 u0 = kp[0];
        uint4 u1 = kp[1];
        float acc = qreg[0]*bflo(u0.x) + qreg[1]*bfhi(u0.x)
                  + qreg[2]*bflo(u0.y) + qreg[3]*bfhi(u0.y)
                  + qreg[4]*bflo(u0.z) + qreg[5]*bfhi(u0.z)
                  + qreg[6]*bflo(u0.w) + qreg[7]*bfhi(u0.w);
        acc += qreg[8]*bflo(u1.x)  + qreg[9]*bfhi(u1.x)
             + qreg[10]*bflo(u1.y) + qreg[11]*bfhi(u1.y)
             + qreg[12]*bflo(u1.z) + qreg[13]*bfhi(u1.z)
             + qreg[14]*bflo(u1.w) + qreg[15]*bfhi(u1.w);
        acc += __shfl_xor(acc, 1, 64);
        acc += __shfl_xor(acc, 2, 64);
        acc += __shfl_xor(acc, 4, 64);
        if (part == 0) qk[j][hh] = acc * 0.08838834764831845f;  // 1/sqrt(128)
    }
    __syncthreads();

    // ---- edge MLP layer 1: (qk||e) (9) -> 18, gelu
    for (int id = t; id < NNB*18; id += 256){
        int j = id/18, u = id%18;
        float acc = eb1[u];
        #pragma unroll
        for (int k = 0; k < 8; k++) acc += qk[j][k]*ew1[k*18+u];
        acc += ej[j]*ew1[8*18+u];
        t18[j][u] = gelu_t(acc);
    }
    __syncthreads();
    // ---- edge MLP layer 2: 18 -> 8
    if (t < NNB*HEADS){
        int j = t/HEADS, h2 = t%HEADS;
        float acc = eb2[h2];
        #pragma unroll
        for (int k = 0; k < 18; k++) acc += t18[j][k]*ew2[k*HEADS+h2];
        lg[j][h2] = acc;
    }
    __syncthreads();

    // ---- precompute gelu(lg) once into qk (dead after edge MLP1)
    if (t < NNB*HEADS) qk[t/HEADS][t%HEADS] = gelu_t(lg[t/HEADS][t%HEADS]);
    __syncthreads();

    // ---- coord MLP: glg (8) -> 64 gelu -> 8
    for (int id = t; id < NNB*64; id += 256){
        int j = id/64, u = id%64;
        float acc = cb1[u];
        #pragma unroll
        for (int k = 0; k < 8; k++) acc += qk[j][k]*cw1[k*64+u];
        t64s[j][u] = gelu_t(acc);
    }
    __syncthreads();
    if (t < NNB*HEADS){
        int j = t/HEADS, h2 = t%HEADS;
        float acc = cb2[h2];
        #pragma unroll 8
        for (int k = 0; k < 64; k++) acc += t64s[j][k]*cw2[k*HEADS+h2];
        cwh[j][h2] = acc;
    }
    __syncthreads();

    // ---- per-neighbor coord weight (t<30) | wave-parallel softmax (t in [64,128))
    if (t < NNB){
        float acc = 0.0f;
        #pragma unroll
        for (int h2 = 0; h2 < HEADS; h2++) acc += cwh[t][h2]*c_comb[h2];
        wj[t] = acc;
    }
    if (t >= 64 && t < 128){
        int h2 = (t-64) >> 3, sub = t & 7;   // 8 lanes per head
        float v0 = lg[sub][h2];
        float v1 = lg[sub+8][h2];
        float v2 = lg[sub+16][h2];
        float v3 = (sub < 6) ? lg[sub+24][h2] : -1e30f;
        float m = fmaxf(fmaxf(v0,v1), fmaxf(v2,v3));
        m = fmaxf(m, __shfl_xor(m, 1, 64));
        m = fmaxf(m, __shfl_xor(m, 2, 64));
        m = fmaxf(m, __shfl_xor(m, 4, 64));
        float p0 = expf(v0-m), p1 = expf(v1-m), p2 = expf(v2-m);
        float p3 = (sub < 6) ? expf(v3-m) : 0.0f;
        float l = p0+p1+p2+p3;
        l += __shfl_xor(l, 1, 64);
        l += __shfl_xor(l, 2, 64);
        l += __shfl_xor(l, 4, 64);
        float rl = 1.0f/l;
        attn[sub][h2]    = p0*rl;
        attn[sub+8][h2]  = p1*rl;
        attn[sub+16][h2] = p2*rl;
        if (sub < 6) attn[sub+24][h2] = p3*rl;
    }
    __syncthreads();

    // ---- coordinate update
    if (t < 3){
        float acc = 0.0f;
        for (int j = 0; j < NNB; j++) acc += wj[j]*reln[j][t];
        cout[(b*NV+i)*3+t] = cin[(b*NV+i)*3+t] + acc;
    }

    // ---- attn @ V (bf16) -> LDS As
    int hv = t >> 5;
    float ax = 0.f, ay = 0.f, az = 0.f, aw = 0.f;
    for (int j = 0; j < NNB; j++){
        float a = attn[j][hv];
        uint2 v = *(const uint2*)&kvh[(size_t)(b*NV+jid[j])*2048 + 1024 + t*4];
        ax += a*bflo(v.x); ay += a*bfhi(v.x); az += a*bflo(v.y); aw += a*bfhi(v.y);
    }
    *(float4*)&As[t*4] = make_float4(ax, ay, az, aw);
    __syncthreads();

    // ---- out-proj (1024 -> 64): 4 partials per output dim
    int d = t & 63, prt = t >> 6;
    {
        float acc = 0.0f;
        const float* as = &As[prt*256];
        const float* wp = &out_w[(size_t)prt*256*DIM + d];
        #pragma unroll 8
        for (int k = 0; k < 256; k++) acc += as[k]*wp[k*DIM];
        red[t] = acc;
    }
    __syncthreads();
    if (t < 64){
        float r = red[t] + red[t+64] + red[t+128] + red[t+192];
        float v = h[(size_t)row*DIM + t] + r + out_b[t];
        hsr[t] = v;
        // LN2 (t<64 is one wave)
        float s = v;
        #pragma unroll
        for (int m = 32; m >= 1; m >>= 1) s += __shfl_xor(s, m, 64);
        float mu = s*(1.0f/64.0f);
        float dd = v - mu;
        float vv = dd*dd;
        #pragma unroll
        for (int m = 32; m >= 1; m >>= 1) vv += __shfl_xor(vv, m, 64);
        ys[t] = dd / sqrtf(vv*(1.0f/64.0f) + 1e-5f) * g2[t] + b2[t];
    }
    __syncthreads();

    // ---- FFN1: 64 -> 256, gelu (all 256 threads)
    {
        float u = fb1[t];
        #pragma unroll 8
        for (int k = 0; k < 64; k++) u += ys[k]*fw1[k*256 + t];
        us[t] = gelu_t(u);
    }
    __syncthreads();

    // ---- FFN2: 256 -> 64, 4 partials per output dim (all 256 threads)
    {
        float f2 = 0.0f;
        const float* up = &us[prt*64];
        const float* wp2 = &fw2[(size_t)prt*64*DIM + d];
        #pragma unroll 8
        for (int k = 0; k < 64; k++) f2 += up[k]*wp2[k*DIM];
        red[t] = f2;
    }
    __syncthreads();
    if (t < 64){
        float f2 = fb2[t] + red[t] + red[t+64] + red[t+128] + red[t+192];
        h[(size_t)row*DIM + t] = hsr[t] + f2;
    }
}

// ---------------------------------------------------------------- classifier + softmax
__global__ __launch_bounds__(64) void k_cls(const float* __restrict__ h,
                                            const float* __restrict__ cls_w,
                                            const float* __restrict__ cls_b,
                                            float* __restrict__ out){
    int row = blockIdx.x;
    int t = threadIdx.x;
    __shared__ float lg[20];
    if (t < 20){
        float acc = cls_b[t];
        #pragma unroll 8
        for (int k = 0; k < 64; k++) acc += h[row*DIM+k]*cls_w[k*20+t];
        lg[t] = acc;
    }
    __syncthreads();
    if (t < 20){
        float m = -1e30f;
        for (int c = 0; c < 20; c++) m = fmaxf(m, lg[c]);
        float l = 0.0f;
        for (int c = 0; c < 20; c++) l += expf(lg[c]-m);
        out[row*20+t] = expf(lg[t]-m)/l;
    }
}

extern "C" void kernel_launch(void* const* d_in, const int* in_sizes, int n_in,
                              void* d_out, int out_size, void* d_ws, size_t ws_size,
                              hipStream_t stream) {
    const float* feats = (const float*)d_in[0];
    const float* coors = (const float*)d_in[1];
    const float* edges = (const float*)d_in[2];
    // d_in[3] = mask (all true) — unused
    const float* fe_w  = (const float*)d_in[4];
    const float* fe_b  = (const float*)d_in[5];
    const float* ln1_g = (const float*)d_in[6];
    const float* ln1_b = (const float*)d_in[7];
    const float* qkv_w = (const float*)d_in[8];
    const float* out_w = (const float*)d_in[9];
    const float* out_b = (const float*)d_in[10];
    const float* ew1   = (const float*)d_in[11];
    const float* eb1   = (const float*)d_in[12];
    const float* ew2   = (const float*)d_in[13];
    const float* eb2   = (const float*)d_in[14];
    const float* cw1   = (const float*)d_in[15];
    const float* cb1   = (const float*)d_in[16];
    const float* cw2   = (const float*)d_in[17];
    const float* cb2   = (const float*)d_in[18];
    const float* c_scale = (const float*)d_in[19];
    const float* c_comb  = (const float*)d_in[20];
    const float* ln2_g = (const float*)d_in[21];
    const float* ln2_b = (const float*)d_in[22];
    const float* fw1   = (const float*)d_in[23];
    const float* fb1   = (const float*)d_in[24];
    const float* fw2   = (const float*)d_in[25];
    const float* fb2   = (const float*)d_in[26];
    const float* cls_w = (const float*)d_in[27];
    const float* cls_b = (const float*)d_in[28];

    float* ws   = (float*)d_ws;
    float* h    = ws;                                  // 1024*64
    float* cA   = h + BN*DIM;                          // 1024*3
    float* cB   = cA + BN*3;                           // 1024*3
    float* qf   = cB + BN*3;                           // 1024*1024 f32 (4 MB): Q
    unsigned short* kvh = (unsigned short*)(qf + (size_t)BN*INNER); // 1024*2048 bf16 (4 MB): K|V
    int*   idx  = (int*)(kvh + (size_t)BN*2048);       // 1024*30

    k_embed<<<BN, 64, 0, stream>>>(feats, coors, fe_w, fe_b, h, cA);

    float* cin = cA; float* cout = cB;
    for (int l = 0; l < 8; l++){
        k_head<<<640, 256, 0, stream>>>(h, ln1_g + l*DIM, ln1_b + l*DIM,
                                        qkv_w + (size_t)l*DIM*3*INNER,
                                        qf, kvh, cin, idx);
        k_layer<<<BN, 256, 0, stream>>>(qf, kvh, idx, cin, cout, edges, h,
                                        ew1 + l*9*18,  eb1 + l*18,
                                        ew2 + l*18*8,  eb2 + l*8,
                                        cw1 + l*8*64,  cb1 + l*64,
                                        cw2 + l*64*8,  cb2 + l*8,
                                        c_scale + l,   c_comb + l*8,
                                        out_w + (size_t)l*INNER*DIM, out_b + l*DIM,
                                        ln2_g + l*DIM, ln2_b + l*DIM,
                                        fw1 + (size_t)l*DIM*256, fb1 + l*256,
                                        fw2 + (size_t)l*256*DIM, fb2 + l*64);
        float* tmp = cin; cin = cout; cout = tmp;
    }

    k_cls<<<BN, 64, 0, stream>>>(h, cls_w, cls_b, (float*)d_out);
}